// Round 1
// baseline (514.668 us; speedup 1.0000x reference)
//
#include <hip/hip_runtime.h>
#include <hip/hip_bf16.h>
#include <hip/hip_cooperative_groups.h>
#include <stdint.h>

namespace cg = cooperative_groups;

typedef short s16x8 __attribute__((ext_vector_type(8)));
typedef float f32x4 __attribute__((ext_vector_type(4)));
typedef unsigned short u16;
typedef unsigned int u32;
typedef unsigned long long u64;

__device__ __forceinline__ float bf2f(u16 v){
  union { u32 u; float f; } c; c.u = ((u32)v) << 16; return c.f;
}

__device__ __forceinline__ u16 f2bf(float f){
  u32 u = __float_as_uint(f);
  u32 r = (u + 0x7FFFu + ((u >> 16) & 1u)) >> 16;   // round-to-nearest-even
  return (u16)r;
}

__device__ __forceinline__ uint4 pack8(float4 a, float4 b){
  union { uint4 v; u16 s[8]; } o;
  o.s[0]=f2bf(a.x); o.s[1]=f2bf(a.y); o.s[2]=f2bf(a.z); o.s[3]=f2bf(a.w);
  o.s[4]=f2bf(b.x); o.s[5]=f2bf(b.y); o.s[6]=f2bf(b.z); o.s[7]=f2bf(b.w);
  return o.v;
}

// ---------------- dtype detector: 1 wave, writes flag (1 = fp32 inputs) ----------------
__global__ __launch_bounds__(64) void k_detect(const u32* __restrict__ x, int* __restrict__ flag){
  int lane = threadIdx.x;
  int cnt = 0;
  for (int i = lane; i < 4096; i += 64){
    u32 w = x[i];
    int ex = (w >> 7) & 0xFF;
    cnt += (ex >= 140) ? 1 : 0;
  }
  #pragma unroll
  for (int off = 32; off; off >>= 1) cnt += __shfl_xor(cnt, off, 64);
  if (lane == 0) *flag = (cnt > 256) ? 1 : 0;
}

// ---------------- flag-aware zero-fill of d_out ----------------
__global__ __launch_bounds__(256) void k_zero(uint4* __restrict__ out, const int* __restrict__ flag,
                                              int out_size){
  int is_f32 = *flag;
  size_t words = (size_t)out_size >> (is_f32 ? 0 : 1);
  size_t n4 = words >> 2;
  size_t i = (size_t)blockIdx.x * 256 + threadIdx.x;
  uint4 z = make_uint4(0, 0, 0, 0);
  for (; i < n4; i += (size_t)gridDim.x * 256) out[i] = z;
}

// ---------------- x -> bf16 copy/convert ----------------
__global__ __launch_bounds__(256) void k_cvt_x(const void* __restrict__ xv, const int* __restrict__ flag,
                                               u16* __restrict__ xb){
  int is_f32 = *flag;
  size_t base = ((size_t)blockIdx.x * 256 + threadIdx.x) << 3;
  if (is_f32){
    const float* xf = (const float*)xv;
    float4 a = *(const float4*)(xf + base);
    float4 b = *(const float4*)(xf + base + 4);
    *(uint4*)(xb + base) = pack8(a, b);
  } else {
    *(uint4*)(xb + base) = *(const uint4*)((const u16*)xv + base);
  }
}

// ---------------- W (e,d,f) -> WT bf16 (e,f,d) transpose/convert ----------------
__global__ __launch_bounds__(256) void k_cvt_wt(const void* __restrict__ Wv, const int* __restrict__ flag,
                                                u16* __restrict__ WT){
  __shared__ u16 tile[64][72];
  int is_f32 = *flag;
  int bx = blockIdx.x;
  int e = bx >> 8, t2 = bx & 255;
  int td = (t2 >> 4) << 6, tf = (t2 & 15) << 6;
  int tid = threadIdx.x;
  #pragma unroll
  for (int i = 0; i < 2; i++){
    int id = tid + (i << 8);
    int row = id >> 3, c8 = id & 7;
    size_t src = ((size_t)(e*1024 + td + row))*1024 + tf + (c8 << 3);
    uint4 v;
    if (is_f32){
      const float* wf = (const float*)Wv;
      v = pack8(*(const float4*)(wf + src), *(const float4*)(wf + src + 4));
    } else {
      v = *(const uint4*)((const u16*)Wv + src);
    }
    *(uint4*)&tile[row][c8 << 3] = v;
  }
  __syncthreads();
  #pragma unroll
  for (int i = 0; i < 2; i++){
    int id = tid + (i << 8);
    int frow = id >> 3, c8 = id & 7;
    union { uint4 v; u16 s[8]; } o;
    #pragma unroll
    for (int j = 0; j < 8; j++) o.s[j] = tile[(c8 << 3) + j][frow];
    *(uint4*)(WT + ((size_t)(e*1024 + tf + frow))*1024 + td + (c8 << 3)) = o.v;
  }
}

// ---------------- gate logits: (B,N,E) fp32 ----------------
__global__ __launch_bounds__(256) void k_logits(const void* __restrict__ xv, const void* __restrict__ gwv,
                                                const int* __restrict__ flag, float* __restrict__ logits){
  int is_f32 = *flag;
  int tid  = threadIdx.x;
  int wave = tid >> 6, lane = tid & 63;
  int token = (blockIdx.x << 2) + wave;
  float xf[16];
  float acc[8];
  #pragma unroll
  for (int e = 0; e < 8; e++) acc[e] = 0.f;

  if (is_f32){
    const float* xr = (const float*)xv + ((size_t)token << 10) + (lane << 4);
    #pragma unroll
    for (int q = 0; q < 4; q++){
      float4 v = *(const float4*)(xr + (q << 2));
      xf[q*4+0]=v.x; xf[q*4+1]=v.y; xf[q*4+2]=v.z; xf[q*4+3]=v.w;
    }
    const float* gw = (const float*)gwv;
    #pragma unroll
    for (int j = 0; j < 16; j++){
      const float* wr = gw + (((size_t)(lane << 4) + j) << 3);
      float4 w0 = *(const float4*)wr;
      float4 w1 = *(const float4*)(wr + 4);
      float xvv = xf[j];
      acc[0] += xvv*w0.x; acc[1] += xvv*w0.y; acc[2] += xvv*w0.z; acc[3] += xvv*w0.w;
      acc[4] += xvv*w1.x; acc[5] += xvv*w1.y; acc[6] += xvv*w1.z; acc[7] += xvv*w1.w;
    }
  } else {
    const u16* xr = (const u16*)xv + ((size_t)token << 10) + (lane << 4);
    union { uint4 v; u16 s[8]; } xa, xb;
    xa.v = *(const uint4*)xr;
    xb.v = *(const uint4*)(xr + 8);
    #pragma unroll
    for (int j = 0; j < 8; j++){ xf[j] = bf2f(xa.s[j]); xf[8 + j] = bf2f(xb.s[j]); }
    const u16* gw = (const u16*)gwv;
    #pragma unroll
    for (int j = 0; j < 16; j++){
      union { uint4 v; u16 s[8]; } wu;
      wu.v = *(const uint4*)(gw + (((lane << 4) + j) << 3));
      float xvv = xf[j];
      #pragma unroll
      for (int e = 0; e < 8; e++) acc[e] += xvv * bf2f(wu.s[e]);
    }
  }
  #pragma unroll
  for (int off = 32; off; off >>= 1){
    #pragma unroll
    for (int e = 0; e < 8; e++) acc[e] += __shfl_xor(acc[e], off, 64);
  }
  if (lane == 0){
    float4 a0 = make_float4(acc[0], acc[1], acc[2], acc[3]);
    float4 a1 = make_float4(acc[4], acc[5], acc[6], acc[7]);
    float* op = logits + ((size_t)token << 3);
    *(float4*)op = a0;
    *(float4*)(op + 4) = a1;
  }
}

// ---------------- sinkhorn v2: cooperative grid, potentials form ----------------
// 64 blocks x 256 threads = 16384 threads = one per (b,n) token row.
// Per thread: c[8] = current log-matrix row (registers). Per iteration:
//   col LSE over n: wave shfl reduce -> LDS cross-wave -> per-block (max,sumexp)
//   partial in global scratch -> ONE grid.sync -> 16-partial online-LSE merge.
//   row LSE over e: thread-local, no comms.
// Scratch double-buffered by iteration parity so one sync/iter suffices.
__global__ __launch_bounds__(256) void k_sinkhorn_coop(float* __restrict__ gates,
                                                       float* __restrict__ part){
  cg::grid_group grid = cg::this_grid();
  __shared__ float wredm[4][8];
  __shared__ float wreds[4][8];
  __shared__ float blkm[8];
  __shared__ float a_s[8];
  int tid  = threadIdx.x;
  int wave = tid >> 6, lane = tid & 63;
  int g = blockIdx.x * 256 + tid;            // flat token id: b = g>>12, n = g&4095
  int bblk0 = (blockIdx.x >> 4) << 4;        // first block of my batch (16 blocks/batch)
  float* gp = gates + ((size_t)g << 3);
  float c[8];
  {
    float4 v0 = *(const float4*)gp;
    float4 v1 = *(const float4*)(gp + 4);
    c[0]=v0.x; c[1]=v0.y; c[2]=v0.z; c[3]=v0.w;
    c[4]=v1.x; c[5]=v1.y; c[6]=v1.z; c[7]=v1.w;
    #pragma unroll
    for (int e = 0; e < 8; e++) c[e] = logf(fmaxf(c[e], 1e-6f));
  }

  for (int it = 0; it < 8; it++){
    int base = (it & 1) << 10;               // double-buffered scratch: 1024 floats each

    // ---- column LSE over tokens (per e, per batch) ----
    float m[8];
    #pragma unroll
    for (int e = 0; e < 8; e++){
      float v = c[e];
      #pragma unroll
      for (int off = 32; off; off >>= 1) v = fmaxf(v, __shfl_xor(v, off, 64));
      m[e] = v;
    }
    if (lane == 0){
      #pragma unroll
      for (int e = 0; e < 8; e++) wredm[wave][e] = m[e];
    }
    __syncthreads();
    #pragma unroll
    for (int e = 0; e < 8; e++)
      m[e] = fmaxf(fmaxf(wredm[0][e], wredm[1][e]), fmaxf(wredm[2][e], wredm[3][e]));
    if (tid == 0){
      #pragma unroll
      for (int e = 0; e < 8; e++) blkm[e] = m[e];   // static-indexed copy for runtime access below
    }
    float s[8];
    #pragma unroll
    for (int e = 0; e < 8; e++){
      float v = expf(c[e] - m[e]);
      #pragma unroll
      for (int off = 32; off; off >>= 1) v += __shfl_xor(v, off, 64);
      s[e] = v;
    }
    if (lane == 0){
      #pragma unroll
      for (int e = 0; e < 8; e++) wreds[wave][e] = s[e];
    }
    __syncthreads();
    if (tid < 8){
      float sb = wreds[0][tid] + wreds[1][tid] + wreds[2][tid] + wreds[3][tid];
      float* pp = part + base + (((blockIdx.x << 3) + tid) << 1);
      pp[0] = blkm[tid];
      pp[1] = sb;
    }
    __threadfence();
    grid.sync();
    if (tid < 8){
      float M = -3.0e38f, S = 0.f;
      for (int p = 0; p < 16; p++){
        const float* pp = part + base + ((((bblk0 + p) << 3) + tid) << 1);
        float mp = pp[0], sp = pp[1];
        float nM = fmaxf(M, mp);
        S = S * expf(M - nM) + sp * expf(mp - nM);
        M = nM;
      }
      a_s[tid] = M + logf(S);
    }
    __syncthreads();
    #pragma unroll
    for (int e = 0; e < 8; e++) c[e] -= a_s[e];

    // ---- row LSE over experts (thread-local) ----
    float rm = c[0];
    #pragma unroll
    for (int e = 1; e < 8; e++) rm = fmaxf(rm, c[e]);
    float rs = 0.f;
    #pragma unroll
    for (int e = 0; e < 8; e++) rs += expf(c[e] - rm);
    float rl = rm + logf(rs);
    #pragma unroll
    for (int e = 0; e < 8; e++) c[e] -= rl;
  }

  float4 o0 = make_float4(expf(c[0]), expf(c[1]), expf(c[2]), expf(c[3]));
  float4 o1 = make_float4(expf(c[4]), expf(c[5]), expf(c[6]), expf(c[7]));
  *(float4*)gp = o0;
  *(float4*)(gp + 4) = o1;
}

// ---------------- top-512 via exact rank-by-counting, v2 ----------------
// rank(i) = #{j<i: v_j >= v_i} + #{j>i: v_j > v_i}  == jax top_k order, single compare per pair.
// Grid: 1024 blocks = 32 (b,e)-columns x 32 slices of 128 tokens. Block: 256 threads.
__global__ __launch_bounds__(256) void k_rank(const float* __restrict__ gates,
                                              int* __restrict__ routed, int* __restrict__ winner){
  __shared__ u32 ord_s[4096];
  __shared__ u32 cnt_s[1024];    // [js][local_token]
  int bx = blockIdx.x;
  int be = bx >> 5;              // 0..31
  int b = be >> 3, e = be & 7;
  int slice = bx & 31;           // 0..31
  int tid = threadIdx.x;
  const float* gb = gates + (size_t)b * (4096 * 8);
  for (int i = tid; i < 4096; i += 256){
    float v = gb[(i << 3) + e];
    u32 fb = __float_as_uint(v);
    ord_s[i] = fb ^ ((fb >> 31) ? 0xFFFFFFFFu : 0x80000000u);   // monotone total order
  }
  __syncthreads();

  int tg = tid & 31;             // token group: 4 tokens
  int js = tid >> 5;             // j-slice: 0..7, 512 j's each
  int i0 = (slice << 7) + (tg << 2);          // first of my 4 tokens (4-aligned)
  int gchunk = i0 & ~7;                       // the 8-chunk containing all 4 tokens
  u32 v0 = ord_s[i0], v1 = ord_s[i0+1], v2 = ord_s[i0+2], v3 = ord_s[i0+3];
  int jlo = js << 9, jhi = jlo + 512;
  int c0 = 0, c1 = 0, c2 = 0, c3 = 0;

  // span A: chunks entirely below gchunk -> predicate >=
  int endA = min(jhi, gchunk);
  for (int j = jlo; j < endA; j += 8){
    uint4 w0 = *(const uint4*)&ord_s[j];
    uint4 w1 = *(const uint4*)&ord_s[j + 4];
    c0 += (w0.x>=v0)+(w0.y>=v0)+(w0.z>=v0)+(w0.w>=v0)+(w1.x>=v0)+(w1.y>=v0)+(w1.z>=v0)+(w1.w>=v0);
    c1 += (w0.x>=v1)+(w0.y>=v1)+(w0.z>=v1)+(w0.w>=v1)+(w1.x>=v1)+(w1.y>=v1)+(w1.z>=v1)+(w1.w>=v1);
    c2 += (w0.x>=v2)+(w0.y>=v2)+(w0.z>=v2)+(w0.w>=v2)+(w1.x>=v2)+(w1.y>=v2)+(w1.z>=v2)+(w1.w>=v2);
    c3 += (w0.x>=v3)+(w0.y>=v3)+(w0.z>=v3)+(w0.w>=v3)+(w1.x>=v3)+(w1.y>=v3)+(w1.z>=v3)+(w1.w>=v3);
  }
  // span B: chunks entirely above gchunk -> predicate >
  int begB = max(jlo, gchunk + 8);
  for (int j = begB; j < jhi; j += 8){
    uint4 w0 = *(const uint4*)&ord_s[j];
    uint4 w1 = *(const uint4*)&ord_s[j + 4];
    c0 += (w0.x>v0)+(w0.y>v0)+(w0.z>v0)+(w0.w>v0)+(w1.x>v0)+(w1.y>v0)+(w1.z>v0)+(w1.w>v0);
    c1 += (w0.x>v1)+(w0.y>v1)+(w0.z>v1)+(w0.w>v1)+(w1.x>v1)+(w1.y>v1)+(w1.z>v1)+(w1.w>v1);
    c2 += (w0.x>v2)+(w0.y>v2)+(w0.z>v2)+(w0.w>v2)+(w1.x>v2)+(w1.y>v2)+(w1.z>v2)+(w1.w>v2);
    c3 += (w0.x>v3)+(w0.y>v3)+(w0.z>v3)+(w0.w>v3)+(w1.x>v3)+(w1.y>v3)+(w1.z>v3)+(w1.w>v3);
  }
  // boundary chunk (contains my 4 tokens) — element-wise j<i test
  if (gchunk >= jlo && gchunk < jhi){
    int base_off = i0 & 7;       // i0 - gchunk: 0 or 4
    #pragma unroll
    for (int jj = 0; jj < 8; jj++){
      u32 w = ord_s[gchunk + jj];
      c0 += (jj < base_off + 0) ? (w >= v0) : (w > v0);
      c1 += (jj < base_off + 1) ? (w >= v1) : (w > v1);
      c2 += (jj < base_off + 2) ? (w >= v2) : (w > v2);
      c3 += (jj < base_off + 3) ? (w >= v3) : (w > v3);
    }
  }
  int lt = tg << 2;              // local token base
  cnt_s[(js << 7) + lt + 0] = c0;
  cnt_s[(js << 7) + lt + 1] = c1;
  cnt_s[(js << 7) + lt + 2] = c2;
  cnt_s[(js << 7) + lt + 3] = c3;
  __syncthreads();
  if (tid < 128){
    int rank = 0;
    #pragma unroll
    for (int s = 0; s < 8; s++) rank += cnt_s[(s << 7) + tid];
    int i = (slice << 7) + tid;
    if (rank < 512){
      routed[(be << 9) + rank] = i;
      atomicMax(&winner[(b << 12) + i], (rank << 3) | e);   // numpy last-write-wins: max (m,e)
    }
  }
}

// ---------------- fast gathered GEMM: pre-converted bf16 x and (e,f,d) WT ----------------
__global__ __launch_bounds__(256) void k_gemm_fast(const u16* __restrict__ xb, const u16* __restrict__ WT,
                                                   const float* __restrict__ gates,
                                                   const int* __restrict__ routed,
                                                   const int* __restrict__ winner,
                                                   const int* __restrict__ flag,
                                                   void* __restrict__ outv){
  __shared__ u16 As[128 * 32];
  __shared__ u16 Bs[128 * 32];
  __shared__ int   tok_s[128];
  __shared__ float gate_s[128];
  __shared__ int   flg_s[128];
  int is_f32 = *flag;
  int bx = blockIdx.x;
  int gemm = bx >> 5, tile = bx & 31;
  int b = gemm >> 3, e = gemm & 7;
  int mt = tile & 3, nt = tile >> 2;
  int tid = threadIdx.x;
  int w = tid >> 6, lane = tid & 63;
  int quad = lane >> 4, l16 = lane & 15;

  const int* idx_base = routed + (((b << 3) + e) << 9) + (mt << 7);

  if (tid < 128){
    int tok = idx_base[tid];
    int mg  = (mt << 7) + tid;
    int win = winner[(b << 12) + tok];
    tok_s[tid]  = tok;
    flg_s[tid]  = (win == ((mg << 3) | e)) ? 1 : 0;
    gate_s[tid] = gates[((((size_t)b << 12) + tok) << 3) + e];
  }
  __syncthreads();

  int r0 = tid >> 2;
  int ch = tid & 3;
  int r1 = r0 + 64;
  const u16* gA0 = xb + ((((size_t)b << 12) + tok_s[r0]) << 10) + (ch << 3);
  const u16* gA1 = xb + ((((size_t)b << 12) + tok_s[r1]) << 10) + (ch << 3);
  int f0 = nt << 7;
  const u16* gB0 = WT + ((((size_t)e << 10) + f0 + r0) << 10) + (ch << 3);
  const u16* gB1 = WT + ((((size_t)e << 10) + f0 + r1) << 10) + (ch << 3);

  f32x4 acc[4][4] = {};
  int wm = (w & 1) << 6, wn = (w >> 1) << 6;

  for (int k0 = 0; k0 < 1024; k0 += 32){
    uint4 a0 = *(const uint4*)(gA0 + k0);
    uint4 a1 = *(const uint4*)(gA1 + k0);
    uint4 b0 = *(const uint4*)(gB0 + k0);
    uint4 b1 = *(const uint4*)(gB1 + k0);
    *(uint4*)&As[(r0 << 5) + (ch << 3)] = a0;
    *(uint4*)&As[(r1 << 5) + (ch << 3)] = a1;
    *(uint4*)&Bs[(r0 << 5) + (ch << 3)] = b0;
    *(uint4*)&Bs[(r1 << 5) + (ch << 3)] = b1;
    __syncthreads();
    s16x8 af[4], bv[4];
    #pragma unroll
    for (int im = 0; im < 4; im++)
      af[im] = *(const s16x8*)&As[((wm + (im << 4) + l16) << 5) + (quad << 3)];
    #pragma unroll
    for (int in = 0; in < 4; in++)
      bv[in] = *(const s16x8*)&Bs[((wn + (in << 4) + l16) << 5) + (quad << 3)];
    __syncthreads();
    #pragma unroll
    for (int im = 0; im < 4; im++){
      #pragma unroll
      for (int in = 0; in < 4; in++)
        acc[im][in] = __builtin_amdgcn_mfma_f32_16x16x32_bf16(af[im], bv[in], acc[im][in], 0, 0, 0);
    }
  }

  #pragma unroll
  for (int im = 0; im < 4; im++){
    #pragma unroll
    for (int r = 0; r < 4; r++){
      int mrow = wm + (im << 4) + (quad << 2) + r;
      if (flg_s[mrow]){
        float g  = gate_s[mrow];
        int tok  = tok_s[mrow];
        size_t obase = ((((size_t)b << 12) + tok) << 10) + f0 + wn + l16;
        if (is_f32){
          float* o32 = (float*)outv;
          #pragma unroll
          for (int in = 0; in < 4; in++) o32[obase + (in << 4)] = acc[im][in][r] * g;
        } else {
          u16* o16 = (u16*)outv;
          #pragma unroll
          for (int in = 0; in < 4; in++) o16[obase + (in << 4)] = f2bf(acc[im][in][r] * g);
        }
      }
    }
  }
}

// ---------------- fallback GEMM (round-4 validated): on-the-fly convert + LDS transpose ----------------
__global__ __launch_bounds__(256) void k_gemm_slow(const void* __restrict__ xv, const void* __restrict__ Wv,
                                                   const float* __restrict__ gates,
                                                   const int* __restrict__ routed,
                                                   const int* __restrict__ winner,
                                                   const int* __restrict__ flag,
                                                   void* __restrict__ outv){
  __shared__ u16 As[128 * 32];
  __shared__ u16 Bw[32 * 132];
  __shared__ u16 Bs[128 * 32];
  __shared__ int   tok_s[128];
  __shared__ float gate_s[128];
  __shared__ int   flg_s[128];
  int is_f32 = *flag;
  int bx = blockIdx.x;
  int gemm = bx >> 5, tile = bx & 31;
  int b = gemm >> 3, e = gemm & 7;
  int mt = tile & 3, nt = tile >> 2;
  int tid = threadIdx.x;
  int w = tid >> 6, lane = tid & 63;
  int quad = lane >> 4, l16 = lane & 15;

  const int* idx_base = routed + (((b << 3) + e) << 9) + (mt << 7);

  if (tid < 128){
    int tok = idx_base[tid];
    int mg  = (mt << 7) + tid;
    int win = winner[(b << 12) + tok];
    tok_s[tid]  = tok;
    flg_s[tid]  = (win == ((mg << 3) | e)) ? 1 : 0;
    gate_s[tid] = gates[((((size_t)b << 12) + tok) << 3) + e];
  }
  __syncthreads();

  int r0 = tid >> 2;
  int ch = tid & 3;
  int r1 = r0 + 64;
  size_t offA0 = ((((size_t)b << 12) + tok_s[r0]) << 10) + (ch << 3);
  size_t offA1 = ((((size_t)b << 12) + tok_s[r1]) << 10) + (ch << 3);
  int f0 = nt << 7;
  int kkB0 = tid >> 4;
  int fcB  = tid & 15;
  size_t offB0 = ((size_t)e << 20) + ((size_t)kkB0 << 10) + f0 + (fcB << 3);
  size_t offB1 = offB0 + ((size_t)16 << 10);
  int f_loc = tid >> 1;
  int half  = tid & 1;

  f32x4 acc[4][4] = {};
  int wm = (w & 1) << 6, wn = (w >> 1) << 6;

  for (int k0 = 0; k0 < 1024; k0 += 32){
    uint4 a0, a1, b0, b1;
    if (is_f32){
      const float* xf = (const float*)xv;
      const float* wf = (const float*)Wv;
      a0 = pack8(*(const float4*)(xf + offA0 + k0), *(const float4*)(xf + offA0 + k0 + 4));
      a1 = pack8(*(const float4*)(xf + offA1 + k0), *(const float4*)(xf + offA1 + k0 + 4));
      b0 = pack8(*(const float4*)(wf + offB0 + ((size_t)k0 << 10)),
                 *(const float4*)(wf + offB0 + ((size_t)k0 << 10) + 4));
      b1 = pack8(*(const float4*)(wf + offB1 + ((size_t)k0 << 10)),
                 *(const float4*)(wf + offB1 + ((size_t)k0 << 10) + 4));
    } else {
      const u16* xh = (const u16*)xv;
      const u16* wh = (const u16*)Wv;
      a0 = *(const uint4*)(xh + offA0 + k0);
      a1 = *(const uint4*)(xh + offA1 + k0);
      b0 = *(const uint4*)(wh + offB0 + ((size_t)k0 << 10));
      b1 = *(const uint4*)(wh + offB1 + ((size_t)k0 << 10));
    }
    *(uint4*)&As[(r0 << 5) + (ch << 3)] = a0;
    *(uint4*)&As[(r1 << 5) + (ch << 3)] = a1;
    *(uint4*)&Bw[kkB0 * 132 + (fcB << 3)] = b0;
    *(uint4*)&Bw[(kkB0 + 16) * 132 + (fcB << 3)] = b1;
    __syncthreads();
    union { uint4 v[2]; u16 s[16]; } tv;
    #pragma unroll
    for (int j = 0; j < 16; j++) tv.s[j] = Bw[((half << 4) + j) * 132 + f_loc];
    *(uint4*)&Bs[(f_loc << 5) + (half << 4)]     = tv.v[0];
    *(uint4*)&Bs[(f_loc << 5) + (half << 4) + 8] = tv.v[1];
    __syncthreads();
    s16x8 af[4], bv[4];
    #pragma unroll
    for (int im = 0; im < 4; im++)
      af[im] = *(const s16x8*)&As[((wm + (im << 4) + l16) << 5) + (quad << 3)];
    #pragma unroll
    for (int in = 0; in < 4; in++)
      bv[in] = *(const s16x8*)&Bs[((wn + (in << 4) + l16) << 5) + (quad << 3)];
    __syncthreads();
    #pragma unroll
    for (int im = 0; im < 4; im++){
      #pragma unroll
      for (int in = 0; in < 4; in++)
        acc[im][in] = __builtin_amdgcn_mfma_f32_16x16x32_bf16(af[im], bv[in], acc[im][in], 0, 0, 0);
    }
  }

  #pragma unroll
  for (int im = 0; im < 4; im++){
    #pragma unroll
    for (int r = 0; r < 4; r++){
      int mrow = wm + (im << 4) + (quad << 2) + r;
      if (flg_s[mrow]){
        float g  = gate_s[mrow];
        int tok  = tok_s[mrow];
        size_t obase = ((((size_t)b << 12) + tok) << 10) + f0 + wn + l16;
        if (is_f32){
          float* o32 = (float*)outv;
          #pragma unroll
          for (int in = 0; in < 4; in++) o32[obase + (in << 4)] = acc[im][in][r] * g;
        } else {
          u16* o16 = (u16*)outv;
          #pragma unroll
          for (int in = 0; in < 4; in++) o16[obase + (in << 4)] = f2bf(acc[im][in][r] * g);
        }
      }
    }
  }
}

extern "C" void kernel_launch(void* const* d_in, const int* in_sizes, int n_in,
                              void* d_out, int out_size, void* d_ws, size_t ws_size,
                              hipStream_t stream){
  const void* x  = d_in[0];   // (4,4096,1024)
  const void* gw = d_in[1];   // (1024,8)
  const void* W  = d_in[2];   // (8,1024,1024)
  char* ws = (char*)d_ws;
  float* gates  = (float*)ws;                               // 524288 B
  int*   winner = (int*)(ws + 524288);                      // 65536 B
  int*   routed = (int*)(ws + 589824);                      // 65536 B
  int*   flag   = (int*)(ws + 655360);                      // 256 B (padded)
  u16*   xb     = (u16*)(ws + 655616);                      // 33554432 B
  u16*   WT     = (u16*)(ws + 655616 + 33554432);           // 16777216 B
  // sinkhorn scratch (8 KB) aliases the head of xb: sinkhorn finishes before
  // k_cvt_x writes xb (same-stream ordering), so the overlap is safe.
  float* sk     = (float*)(ws + 655616);
  size_t need_fast = 655616ull + 33554432ull + 16777216ull; // ~48.6 MiB
  bool fast = ws_size >= need_fast;

  hipMemsetAsync(winner, 0xFF, 65536, stream);
  hipLaunchKernelGGL(k_detect,   dim3(1),    dim3(64),   0, stream, (const u32*)x, flag);
  hipLaunchKernelGGL(k_zero,     dim3(4096), dim3(256),  0, stream, (uint4*)d_out, flag, out_size);
  hipLaunchKernelGGL(k_logits,   dim3(4096), dim3(256),  0, stream, x, gw, flag, gates);
  {
    void* skArgs[] = { (void*)&gates, (void*)&sk };
    hipLaunchCooperativeKernel(k_sinkhorn_coop, dim3(64), dim3(256), skArgs, 0, stream);
  }
  hipLaunchKernelGGL(k_rank,     dim3(1024), dim3(256),  0, stream, gates, routed, winner);
  if (fast){
    hipLaunchKernelGGL(k_cvt_x,  dim3(8192), dim3(256),  0, stream, x, flag, xb);
    hipLaunchKernelGGL(k_cvt_wt, dim3(2048), dim3(256),  0, stream, W, flag, WT);
    hipLaunchKernelGGL(k_gemm_fast, dim3(1024), dim3(256), 0, stream, xb, WT, gates, routed, winner,
                       flag, d_out);
  } else {
    hipLaunchKernelGGL(k_gemm_slow, dim3(1024), dim3(256), 0, stream, x, W, gates, routed, winner,
                       flag, d_out);
  }
}

// Round 2
// 394.565 us; speedup vs baseline: 1.3044x; 1.3044x over previous
//
#include <hip/hip_runtime.h>
#include <hip/hip_bf16.h>
#include <stdint.h>

typedef short s16x8 __attribute__((ext_vector_type(8)));
typedef float f32x4 __attribute__((ext_vector_type(4)));
typedef unsigned short u16;
typedef unsigned int u32;
typedef unsigned long long u64;

__device__ __forceinline__ float bf2f(u16 v){
  union { u32 u; float f; } c; c.u = ((u32)v) << 16; return c.f;
}

__device__ __forceinline__ u16 f2bf(float f){
  u32 u = __float_as_uint(f);
  u32 r = (u + 0x7FFFu + ((u >> 16) & 1u)) >> 16;   // round-to-nearest-even
  return (u16)r;
}

__device__ __forceinline__ uint4 pack8(float4 a, float4 b){
  union { uint4 v; u16 s[8]; } o;
  o.s[0]=f2bf(a.x); o.s[1]=f2bf(a.y); o.s[2]=f2bf(a.z); o.s[3]=f2bf(a.w);
  o.s[4]=f2bf(b.x); o.s[5]=f2bf(b.y); o.s[6]=f2bf(b.z); o.s[7]=f2bf(b.w);
  return o.v;
}

// ---------------- dtype detector: 1 wave, writes flag (1 = fp32 inputs) ----------------
__global__ __launch_bounds__(64) void k_detect(const u32* __restrict__ x, int* __restrict__ flag){
  int lane = threadIdx.x;
  int cnt = 0;
  for (int i = lane; i < 4096; i += 64){
    u32 w = x[i];
    int ex = (w >> 7) & 0xFF;
    cnt += (ex >= 140) ? 1 : 0;
  }
  #pragma unroll
  for (int off = 32; off; off >>= 1) cnt += __shfl_xor(cnt, off, 64);
  if (lane == 0) *flag = (cnt > 256) ? 1 : 0;
}

// ---------------- gate logits: (B,N,E) fp32 ----------------
__global__ __launch_bounds__(256) void k_logits(const void* __restrict__ xv, const void* __restrict__ gwv,
                                                const int* __restrict__ flag, float* __restrict__ logits){
  int is_f32 = *flag;
  int tid  = threadIdx.x;
  int wave = tid >> 6, lane = tid & 63;
  int token = (blockIdx.x << 2) + wave;
  float xf[16];
  float acc[8];
  #pragma unroll
  for (int e = 0; e < 8; e++) acc[e] = 0.f;

  if (is_f32){
    const float* xr = (const float*)xv + ((size_t)token << 10) + (lane << 4);
    #pragma unroll
    for (int q = 0; q < 4; q++){
      float4 v = *(const float4*)(xr + (q << 2));
      xf[q*4+0]=v.x; xf[q*4+1]=v.y; xf[q*4+2]=v.z; xf[q*4+3]=v.w;
    }
    const float* gw = (const float*)gwv;
    #pragma unroll
    for (int j = 0; j < 16; j++){
      const float* wr = gw + (((size_t)(lane << 4) + j) << 3);
      float4 w0 = *(const float4*)wr;
      float4 w1 = *(const float4*)(wr + 4);
      float xvv = xf[j];
      acc[0] += xvv*w0.x; acc[1] += xvv*w0.y; acc[2] += xvv*w0.z; acc[3] += xvv*w0.w;
      acc[4] += xvv*w1.x; acc[5] += xvv*w1.y; acc[6] += xvv*w1.z; acc[7] += xvv*w1.w;
    }
  } else {
    const u16* xr = (const u16*)xv + ((size_t)token << 10) + (lane << 4);
    union { uint4 v; u16 s[8]; } xa, xb;
    xa.v = *(const uint4*)xr;
    xb.v = *(const uint4*)(xr + 8);
    #pragma unroll
    for (int j = 0; j < 8; j++){ xf[j] = bf2f(xa.s[j]); xf[8 + j] = bf2f(xb.s[j]); }
    const u16* gw = (const u16*)gwv;
    #pragma unroll
    for (int j = 0; j < 16; j++){
      union { uint4 v; u16 s[8]; } wu;
      wu.v = *(const uint4*)(gw + (((lane << 4) + j) << 3));
      float xvv = xf[j];
      #pragma unroll
      for (int e = 0; e < 8; e++) acc[e] += xvv * bf2f(wu.s[e]);
    }
  }
  #pragma unroll
  for (int off = 32; off; off >>= 1){
    #pragma unroll
    for (int e = 0; e < 8; e++) acc[e] += __shfl_xor(acc[e], off, 64);
  }
  if (lane == 0){
    float4 a0 = make_float4(acc[0], acc[1], acc[2], acc[3]);
    float4 a1 = make_float4(acc[4], acc[5], acc[6], acc[7]);
    float* op = logits + ((size_t)token << 3);
    *(float4*)op = a0;
    *(float4*)(op + 4) = a1;
  }
}

// ---------------- fused: sinkhorn (blocks 0-3) + cvt_wt + cvt_x + zero (rest) ----------------
// Role layout (mode==1, fast path), grid = 3076 x 1024 threads:
//   bx 0..3      : sinkhorn, one block per batch, rows register-resident
//   bx 4..515    : W -> WT transpose/convert (4 64x64 tiles per block)
//   bx 516..2563 : x -> bf16 copy/convert (8192 u16 per block)
//   bx 2564..3075: zero-fill d_out
// Role layout (mode==0, fallback), grid = 516:
//   bx 0..3 sinkhorn, bx 4..515 zero.
// Roles are independent; sinkhorn runs concurrently under the BW-bound roles.
__global__ __launch_bounds__(1024) void k_fused(float* __restrict__ gates,
                                                const void* __restrict__ xv,
                                                const void* __restrict__ Wv,
                                                const int* __restrict__ flag,
                                                u16* __restrict__ xb,
                                                u16* __restrict__ WT,
                                                uint4* __restrict__ out,
                                                int out_size, int mode){
  __shared__ __align__(16) char smem[36864];   // cvt_wt: 4 x [64][72] u16 tiles; sinkhorn: 144 floats
  int bx = blockIdx.x;
  int tid = threadIdx.x;

  if (bx < 4){
    // ---- sinkhorn: batch = bx, thread owns tokens {tid, tid+1024, tid+2048, tid+3072} ----
    int wave = tid >> 6, lane = tid & 63;
    float* wred = (float*)smem;          // [16][8] cross-wave partials
    float* mbc  = wred + 128;            // [8] column max broadcast
    float* lbc  = mbc + 8;               // [8] column LSE broadcast
    float* gb = gates + ((size_t)bx << 15);
    float c[32];                         // c[q*8+e] = row of token q*1024+tid
    #pragma unroll
    for (int q = 0; q < 4; q++){
      const float* gp = gb + (((q << 10) + tid) << 3);
      float4 v0 = *(const float4*)gp;
      float4 v1 = *(const float4*)(gp + 4);
      c[q*8+0]=v0.x; c[q*8+1]=v0.y; c[q*8+2]=v0.z; c[q*8+3]=v0.w;
      c[q*8+4]=v1.x; c[q*8+5]=v1.y; c[q*8+6]=v1.z; c[q*8+7]=v1.w;
    }
    #pragma unroll
    for (int i = 0; i < 32; i++) c[i] = logf(fmaxf(c[i], 1e-6f));

    for (int it = 0; it < 8; it++){
      // ---- column max over 4096 tokens ----
      #pragma unroll
      for (int e = 0; e < 8; e++){
        float v = fmaxf(fmaxf(c[e], c[8+e]), fmaxf(c[16+e], c[24+e]));
        #pragma unroll
        for (int off = 32; off; off >>= 1) v = fmaxf(v, __shfl_xor(v, off, 64));
        if (lane == 0) wred[(wave << 3) + e] = v;
      }
      __syncthreads();
      if (tid < 8){
        float v = wred[tid];
        #pragma unroll
        for (int w2 = 1; w2 < 16; w2++) v = fmaxf(v, wred[(w2 << 3) + tid]);
        mbc[tid] = v;
      }
      __syncthreads();
      // ---- column sumexp ----
      #pragma unroll
      for (int e = 0; e < 8; e++){
        float m = mbc[e];
        float v = expf(c[e]-m) + expf(c[8+e]-m) + expf(c[16+e]-m) + expf(c[24+e]-m);
        #pragma unroll
        for (int off = 32; off; off >>= 1) v += __shfl_xor(v, off, 64);
        if (lane == 0) wred[(wave << 3) + e] = v;
      }
      __syncthreads();
      if (tid < 8){
        float v = 0.f;
        #pragma unroll
        for (int w2 = 0; w2 < 16; w2++) v += wred[(w2 << 3) + tid];
        lbc[tid] = mbc[tid] + logf(v);
      }
      __syncthreads();
      #pragma unroll
      for (int e = 0; e < 8; e++){
        float a = lbc[e];
        c[e] -= a; c[8+e] -= a; c[16+e] -= a; c[24+e] -= a;
      }
      // ---- row LSE over experts (thread-local) ----
      #pragma unroll
      for (int q = 0; q < 4; q++){
        float rm = c[q*8];
        #pragma unroll
        for (int e = 1; e < 8; e++) rm = fmaxf(rm, c[q*8+e]);
        float rs = 0.f;
        #pragma unroll
        for (int e = 0; e < 8; e++) rs += expf(c[q*8+e] - rm);
        float rl = rm + logf(rs);
        #pragma unroll
        for (int e = 0; e < 8; e++) c[q*8+e] -= rl;
      }
      __syncthreads();
    }
    #pragma unroll
    for (int q = 0; q < 4; q++){
      float* gp = gb + (((q << 10) + tid) << 3);
      float4 o0 = make_float4(expf(c[q*8+0]), expf(c[q*8+1]), expf(c[q*8+2]), expf(c[q*8+3]));
      float4 o1 = make_float4(expf(c[q*8+4]), expf(c[q*8+5]), expf(c[q*8+6]), expf(c[q*8+7]));
      *(float4*)gp = o0;
      *(float4*)(gp + 4) = o1;
    }
    return;
  }

  if (mode == 0){
    // fallback: bx 4..515 zero-fill
    int is_f32 = *flag;
    int rb = bx - 4;
    size_t words = (size_t)out_size >> (is_f32 ? 0 : 1);
    size_t n4 = words >> 2;
    size_t i = (size_t)rb * 1024 + tid;
    uint4 z = make_uint4(0, 0, 0, 0);
    for (; i < n4; i += (size_t)512 * 1024) out[i] = z;
    return;
  }

  if (bx < 516){
    // ---- W (e,d,f) -> WT (e,f,d) bf16: 4 64x64 tiles per block ----
    int is_f32 = *flag;
    int rb = bx - 4;
    int sub = tid >> 8;
    int t = tid & 255;
    int g = (rb << 2) + sub;          // global tile id 0..2047
    int e = g >> 8, t2 = g & 255;
    int td = (t2 >> 4) << 6, tf = (t2 & 15) << 6;
    u16 (*tile)[72] = (u16(*)[72])(smem + (size_t)sub * (64 * 72 * 2));
    #pragma unroll
    for (int i = 0; i < 2; i++){
      int id = t + (i << 8);
      int row = id >> 3, c8 = id & 7;
      size_t src = ((size_t)(e*1024 + td + row))*1024 + tf + (c8 << 3);
      uint4 v;
      if (is_f32){
        const float* wf = (const float*)Wv;
        v = pack8(*(const float4*)(wf + src), *(const float4*)(wf + src + 4));
      } else {
        v = *(const uint4*)((const u16*)Wv + src);
      }
      *(uint4*)&tile[row][c8 << 3] = v;
    }
    __syncthreads();
    #pragma unroll
    for (int i = 0; i < 2; i++){
      int id = t + (i << 8);
      int frow = id >> 3, c8 = id & 7;
      union { uint4 v; u16 s[8]; } o;
      #pragma unroll
      for (int j = 0; j < 8; j++) o.s[j] = tile[(c8 << 3) + j][frow];
      *(uint4*)(WT + ((size_t)(e*1024 + tf + frow))*1024 + td + (c8 << 3)) = o.v;
    }
    return;
  }

  if (bx < 2564){
    // ---- x -> bf16 copy/convert ----
    int is_f32 = *flag;
    int rb = bx - 516;
    size_t base = ((size_t)rb * 1024 + tid) << 3;
    if (is_f32){
      const float* xf = (const float*)xv;
      float4 a = *(const float4*)(xf + base);
      float4 b = *(const float4*)(xf + base + 4);
      *(uint4*)(xb + base) = pack8(a, b);
    } else {
      *(uint4*)(xb + base) = *(const uint4*)((const u16*)xv + base);
    }
    return;
  }

  {
    // ---- zero-fill d_out ----
    int is_f32 = *flag;
    int rb = bx - 2564;
    size_t words = (size_t)out_size >> (is_f32 ? 0 : 1);
    size_t n4 = words >> 2;
    size_t i = (size_t)rb * 1024 + tid;
    uint4 z = make_uint4(0, 0, 0, 0);
    for (; i < n4; i += (size_t)512 * 1024) out[i] = z;
  }
}

// ---------------- top-512 via exact rank-by-counting, v2 ----------------
// rank(i) = #{j<i: v_j >= v_i} + #{j>i: v_j > v_i}  == jax top_k order, single compare per pair.
// Grid: 1024 blocks = 32 (b,e)-columns x 32 slices of 128 tokens. Block: 256 threads.
__global__ __launch_bounds__(256) void k_rank(const float* __restrict__ gates,
                                              int* __restrict__ routed, int* __restrict__ winner){
  __shared__ u32 ord_s[4096];
  __shared__ u32 cnt_s[1024];    // [js][local_token]
  int bx = blockIdx.x;
  int be = bx >> 5;              // 0..31
  int b = be >> 3, e = be & 7;
  int slice = bx & 31;           // 0..31
  int tid = threadIdx.x;
  const float* gb = gates + (size_t)b * (4096 * 8);
  for (int i = tid; i < 4096; i += 256){
    float v = gb[(i << 3) + e];
    u32 fb = __float_as_uint(v);
    ord_s[i] = fb ^ ((fb >> 31) ? 0xFFFFFFFFu : 0x80000000u);   // monotone total order
  }
  __syncthreads();

  int tg = tid & 31;             // token group: 4 tokens
  int js = tid >> 5;             // j-slice: 0..7, 512 j's each
  int i0 = (slice << 7) + (tg << 2);          // first of my 4 tokens (4-aligned)
  int gchunk = i0 & ~7;                       // the 8-chunk containing all 4 tokens
  u32 v0 = ord_s[i0], v1 = ord_s[i0+1], v2 = ord_s[i0+2], v3 = ord_s[i0+3];
  int jlo = js << 9, jhi = jlo + 512;
  int c0 = 0, c1 = 0, c2 = 0, c3 = 0;

  // span A: chunks entirely below gchunk -> predicate >=
  int endA = min(jhi, gchunk);
  for (int j = jlo; j < endA; j += 8){
    uint4 w0 = *(const uint4*)&ord_s[j];
    uint4 w1 = *(const uint4*)&ord_s[j + 4];
    c0 += (w0.x>=v0)+(w0.y>=v0)+(w0.z>=v0)+(w0.w>=v0)+(w1.x>=v0)+(w1.y>=v0)+(w1.z>=v0)+(w1.w>=v0);
    c1 += (w0.x>=v1)+(w0.y>=v1)+(w0.z>=v1)+(w0.w>=v1)+(w1.x>=v1)+(w1.y>=v1)+(w1.z>=v1)+(w1.w>=v1);
    c2 += (w0.x>=v2)+(w0.y>=v2)+(w0.z>=v2)+(w0.w>=v2)+(w1.x>=v2)+(w1.y>=v2)+(w1.z>=v2)+(w1.w>=v2);
    c3 += (w0.x>=v3)+(w0.y>=v3)+(w0.z>=v3)+(w0.w>=v3)+(w1.x>=v3)+(w1.y>=v3)+(w1.z>=v3)+(w1.w>=v3);
  }
  // span B: chunks entirely above gchunk -> predicate >
  int begB = max(jlo, gchunk + 8);
  for (int j = begB; j < jhi; j += 8){
    uint4 w0 = *(const uint4*)&ord_s[j];
    uint4 w1 = *(const uint4*)&ord_s[j + 4];
    c0 += (w0.x>v0)+(w0.y>v0)+(w0.z>v0)+(w0.w>v0)+(w1.x>v0)+(w1.y>v0)+(w1.z>v0)+(w1.w>v0);
    c1 += (w0.x>v1)+(w0.y>v1)+(w0.z>v1)+(w0.w>v1)+(w1.x>v1)+(w1.y>v1)+(w1.z>v1)+(w1.w>v1);
    c2 += (w0.x>v2)+(w0.y>v2)+(w0.z>v2)+(w0.w>v2)+(w1.x>v2)+(w1.y>v2)+(w1.z>v2)+(w1.w>v2);
    c3 += (w0.x>v3)+(w0.y>v3)+(w0.z>v3)+(w0.w>v3)+(w1.x>v3)+(w1.y>v3)+(w1.z>v3)+(w1.w>v3);
  }
  // boundary chunk (contains my 4 tokens) — element-wise j<i test
  if (gchunk >= jlo && gchunk < jhi){
    int base_off = i0 & 7;       // i0 - gchunk: 0 or 4
    #pragma unroll
    for (int jj = 0; jj < 8; jj++){
      u32 w = ord_s[gchunk + jj];
      c0 += (jj < base_off + 0) ? (w >= v0) : (w > v0);
      c1 += (jj < base_off + 1) ? (w >= v1) : (w > v1);
      c2 += (jj < base_off + 2) ? (w >= v2) : (w > v2);
      c3 += (jj < base_off + 3) ? (w >= v3) : (w > v3);
    }
  }
  int lt = tg << 2;              // local token base
  cnt_s[(js << 7) + lt + 0] = c0;
  cnt_s[(js << 7) + lt + 1] = c1;
  cnt_s[(js << 7) + lt + 2] = c2;
  cnt_s[(js << 7) + lt + 3] = c3;
  __syncthreads();
  if (tid < 128){
    int rank = 0;
    #pragma unroll
    for (int s = 0; s < 8; s++) rank += cnt_s[(s << 7) + tid];
    int i = (slice << 7) + tid;
    if (rank < 512){
      routed[(be << 9) + rank] = i;
      atomicMax(&winner[(b << 12) + i], (rank << 3) | e);   // numpy last-write-wins: max (m,e)
    }
  }
}

// ---------------- fast gathered GEMM: pre-converted bf16 x and (e,f,d) WT ----------------
__global__ __launch_bounds__(256) void k_gemm_fast(const u16* __restrict__ xb, const u16* __restrict__ WT,
                                                   const float* __restrict__ gates,
                                                   const int* __restrict__ routed,
                                                   const int* __restrict__ winner,
                                                   const int* __restrict__ flag,
                                                   void* __restrict__ outv){
  __shared__ u16 As[128 * 32];
  __shared__ u16 Bs[128 * 32];
  __shared__ int   tok_s[128];
  __shared__ float gate_s[128];
  __shared__ int   flg_s[128];
  int is_f32 = *flag;
  int bx = blockIdx.x;
  int gemm = bx >> 5, tile = bx & 31;
  int b = gemm >> 3, e = gemm & 7;
  int mt = tile & 3, nt = tile >> 2;
  int tid = threadIdx.x;
  int w = tid >> 6, lane = tid & 63;
  int quad = lane >> 4, l16 = lane & 15;

  const int* idx_base = routed + (((b << 3) + e) << 9) + (mt << 7);

  if (tid < 128){
    int tok = idx_base[tid];
    int mg  = (mt << 7) + tid;
    int win = winner[(b << 12) + tok];
    tok_s[tid]  = tok;
    flg_s[tid]  = (win == ((mg << 3) | e)) ? 1 : 0;
    gate_s[tid] = gates[((((size_t)b << 12) + tok) << 3) + e];
  }
  __syncthreads();

  int r0 = tid >> 2;
  int ch = tid & 3;
  int r1 = r0 + 64;
  const u16* gA0 = xb + ((((size_t)b << 12) + tok_s[r0]) << 10) + (ch << 3);
  const u16* gA1 = xb + ((((size_t)b << 12) + tok_s[r1]) << 10) + (ch << 3);
  int f0 = nt << 7;
  const u16* gB0 = WT + ((((size_t)e << 10) + f0 + r0) << 10) + (ch << 3);
  const u16* gB1 = WT + ((((size_t)e << 10) + f0 + r1) << 10) + (ch << 3);

  f32x4 acc[4][4] = {};
  int wm = (w & 1) << 6, wn = (w >> 1) << 6;

  for (int k0 = 0; k0 < 1024; k0 += 32){
    uint4 a0 = *(const uint4*)(gA0 + k0);
    uint4 a1 = *(const uint4*)(gA1 + k0);
    uint4 b0 = *(const uint4*)(gB0 + k0);
    uint4 b1 = *(const uint4*)(gB1 + k0);
    *(uint4*)&As[(r0 << 5) + (ch << 3)] = a0;
    *(uint4*)&As[(r1 << 5) + (ch << 3)] = a1;
    *(uint4*)&Bs[(r0 << 5) + (ch << 3)] = b0;
    *(uint4*)&Bs[(r1 << 5) + (ch << 3)] = b1;
    __syncthreads();
    s16x8 af[4], bv[4];
    #pragma unroll
    for (int im = 0; im < 4; im++)
      af[im] = *(const s16x8*)&As[((wm + (im << 4) + l16) << 5) + (quad << 3)];
    #pragma unroll
    for (int in = 0; in < 4; in++)
      bv[in] = *(const s16x8*)&Bs[((wn + (in << 4) + l16) << 5) + (quad << 3)];
    __syncthreads();
    #pragma unroll
    for (int im = 0; im < 4; im++){
      #pragma unroll
      for (int in = 0; in < 4; in++)
        acc[im][in] = __builtin_amdgcn_mfma_f32_16x16x32_bf16(af[im], bv[in], acc[im][in], 0, 0, 0);
    }
  }

  #pragma unroll
  for (int im = 0; im < 4; im++){
    #pragma unroll
    for (int r = 0; r < 4; r++){
      int mrow = wm + (im << 4) + (quad << 2) + r;
      if (flg_s[mrow]){
        float g  = gate_s[mrow];
        int tok  = tok_s[mrow];
        size_t obase = ((((size_t)b << 12) + tok) << 10) + f0 + wn + l16;
        if (is_f32){
          float* o32 = (float*)outv;
          #pragma unroll
          for (int in = 0; in < 4; in++) o32[obase + (in << 4)] = acc[im][in][r] * g;
        } else {
          u16* o16 = (u16*)outv;
          #pragma unroll
          for (int in = 0; in < 4; in++) o16[obase + (in << 4)] = f2bf(acc[im][in][r] * g);
        }
      }
    }
  }
}

// ---------------- fallback GEMM (round-4 validated): on-the-fly convert + LDS transpose ----------------
__global__ __launch_bounds__(256) void k_gemm_slow(const void* __restrict__ xv, const void* __restrict__ Wv,
                                                   const float* __restrict__ gates,
                                                   const int* __restrict__ routed,
                                                   const int* __restrict__ winner,
                                                   const int* __restrict__ flag,
                                                   void* __restrict__ outv){
  __shared__ u16 As[128 * 32];
  __shared__ u16 Bw[32 * 132];
  __shared__ u16 Bs[128 * 32];
  __shared__ int   tok_s[128];
  __shared__ float gate_s[128];
  __shared__ int   flg_s[128];
  int is_f32 = *flag;
  int bx = blockIdx.x;
  int gemm = bx >> 5, tile = bx & 31;
  int b = gemm >> 3, e = gemm & 7;
  int mt = tile & 3, nt = tile >> 2;
  int tid = threadIdx.x;
  int w = tid >> 6, lane = tid & 63;
  int quad = lane >> 4, l16 = lane & 15;

  const int* idx_base = routed + (((b << 3) + e) << 9) + (mt << 7);

  if (tid < 128){
    int tok = idx_base[tid];
    int mg  = (mt << 7) + tid;
    int win = winner[(b << 12) + tok];
    tok_s[tid]  = tok;
    flg_s[tid]  = (win == ((mg << 3) | e)) ? 1 : 0;
    gate_s[tid] = gates[((((size_t)b << 12) + tok) << 3) + e];
  }
  __syncthreads();

  int r0 = tid >> 2;
  int ch = tid & 3;
  int r1 = r0 + 64;
  size_t offA0 = ((((size_t)b << 12) + tok_s[r0]) << 10) + (ch << 3);
  size_t offA1 = ((((size_t)b << 12) + tok_s[r1]) << 10) + (ch << 3);
  int f0 = nt << 7;
  int kkB0 = tid >> 4;
  int fcB  = tid & 15;
  size_t offB0 = ((size_t)e << 20) + ((size_t)kkB0 << 10) + f0 + (fcB << 3);
  size_t offB1 = offB0 + ((size_t)16 << 10);
  int f_loc = tid >> 1;
  int half  = tid & 1;

  f32x4 acc[4][4] = {};
  int wm = (w & 1) << 6, wn = (w >> 1) << 6;

  for (int k0 = 0; k0 < 1024; k0 += 32){
    uint4 a0, a1, b0, b1;
    if (is_f32){
      const float* xf = (const float*)xv;
      const float* wf = (const float*)Wv;
      a0 = pack8(*(const float4*)(xf + offA0 + k0), *(const float4*)(xf + offA0 + k0 + 4));
      a1 = pack8(*(const float4*)(xf + offA1 + k0), *(const float4*)(xf + offA1 + k0 + 4));
      b0 = pack8(*(const float4*)(wf + offB0 + ((size_t)k0 << 10)),
                 *(const float4*)(wf + offB0 + ((size_t)k0 << 10) + 4));
      b1 = pack8(*(const float4*)(wf + offB1 + ((size_t)k0 << 10)),
                 *(const float4*)(wf + offB1 + ((size_t)k0 << 10) + 4));
    } else {
      const u16* xh = (const u16*)xv;
      const u16* wh = (const u16*)Wv;
      a0 = *(const uint4*)(xh + offA0 + k0);
      a1 = *(const uint4*)(xh + offA1 + k0);
      b0 = *(const uint4*)(wh + offB0 + ((size_t)k0 << 10));
      b1 = *(const uint4*)(wh + offB1 + ((size_t)k0 << 10));
    }
    *(uint4*)&As[(r0 << 5) + (ch << 3)] = a0;
    *(uint4*)&As[(r1 << 5) + (ch << 3)] = a1;
    *(uint4*)&Bw[kkB0 * 132 + (fcB << 3)] = b0;
    *(uint4*)&Bw[(kkB0 + 16) * 132 + (fcB << 3)] = b1;
    __syncthreads();
    union { uint4 v[2]; u16 s[16]; } tv;
    #pragma unroll
    for (int j = 0; j < 16; j++) tv.s[j] = Bw[((half << 4) + j) * 132 + f_loc];
    *(uint4*)&Bs[(f_loc << 5) + (half << 4)]     = tv.v[0];
    *(uint4*)&Bs[(f_loc << 5) + (half << 4) + 8] = tv.v[1];
    __syncthreads();
    s16x8 af[4], bv[4];
    #pragma unroll
    for (int im = 0; im < 4; im++)
      af[im] = *(const s16x8*)&As[((wm + (im << 4) + l16) << 5) + (quad << 3)];
    #pragma unroll
    for (int in = 0; in < 4; in++)
      bv[in] = *(const s16x8*)&Bs[((wn + (in << 4) + l16) << 5) + (quad << 3)];
    __syncthreads();
    #pragma unroll
    for (int im = 0; im < 4; im++){
      #pragma unroll
      for (int in = 0; in < 4; in++)
        acc[im][in] = __builtin_amdgcn_mfma_f32_16x16x32_bf16(af[im], bv[in], acc[im][in], 0, 0, 0);
    }
  }

  #pragma unroll
  for (int im = 0; im < 4; im++){
    #pragma unroll
    for (int r = 0; r < 4; r++){
      int mrow = wm + (im << 4) + (quad << 2) + r;
      if (flg_s[mrow]){
        float g  = gate_s[mrow];
        int tok  = tok_s[mrow];
        size_t obase = ((((size_t)b << 12) + tok) << 10) + f0 + wn + l16;
        if (is_f32){
          float* o32 = (float*)outv;
          #pragma unroll
          for (int in = 0; in < 4; in++) o32[obase + (in << 4)] = acc[im][in][r] * g;
        } else {
          u16* o16 = (u16*)outv;
          #pragma unroll
          for (int in = 0; in < 4; in++) o16[obase + (in << 4)] = f2bf(acc[im][in][r] * g);
        }
      }
    }
  }
}

extern "C" void kernel_launch(void* const* d_in, const int* in_sizes, int n_in,
                              void* d_out, int out_size, void* d_ws, size_t ws_size,
                              hipStream_t stream){
  const void* x  = d_in[0];   // (4,4096,1024)
  const void* gw = d_in[1];   // (1024,8)
  const void* W  = d_in[2];   // (8,1024,1024)
  char* ws = (char*)d_ws;
  float* gates  = (float*)ws;                               // 524288 B
  int*   winner = (int*)(ws + 524288);                      // 65536 B
  int*   routed = (int*)(ws + 589824);                      // 65536 B
  int*   flag   = (int*)(ws + 655360);                      // 256 B (padded)
  u16*   xb     = (u16*)(ws + 655616);                      // 33554432 B
  u16*   WT     = (u16*)(ws + 655616 + 33554432);           // 16777216 B
  size_t need_fast = 655616ull + 33554432ull + 16777216ull; // ~48.6 MiB
  bool fast = ws_size >= need_fast;

  hipMemsetAsync(winner, 0xFF, 65536, stream);
  hipLaunchKernelGGL(k_detect,   dim3(1),    dim3(64),   0, stream, (const u32*)x, flag);
  hipLaunchKernelGGL(k_logits,   dim3(4096), dim3(256),  0, stream, x, gw, flag, gates);
  if (fast){
    hipLaunchKernelGGL(k_fused, dim3(3076), dim3(1024), 0, stream,
                       gates, x, W, flag, xb, WT, (uint4*)d_out, out_size, 1);
    hipLaunchKernelGGL(k_rank,  dim3(1024), dim3(256),  0, stream, gates, routed, winner);
    hipLaunchKernelGGL(k_gemm_fast, dim3(1024), dim3(256), 0, stream, xb, WT, gates, routed, winner,
                       flag, d_out);
  } else {
    hipLaunchKernelGGL(k_fused, dim3(516), dim3(1024), 0, stream,
                       gates, x, W, flag, xb, WT, (uint4*)d_out, out_size, 0);
    hipLaunchKernelGGL(k_rank,  dim3(1024), dim3(256),  0, stream, gates, routed, winner);
    hipLaunchKernelGGL(k_gemm_slow, dim3(1024), dim3(256), 0, stream, x, W, gates, routed, winner,
                       flag, d_out);
  }
}

// Round 3
// 369.293 us; speedup vs baseline: 1.3937x; 1.0684x over previous
//
#include <hip/hip_runtime.h>
#include <hip/hip_bf16.h>
#include <stdint.h>

typedef short s16x8 __attribute__((ext_vector_type(8)));
typedef float f32x4 __attribute__((ext_vector_type(4)));
typedef unsigned short u16;
typedef unsigned int u32;
typedef unsigned long long u64;

__device__ __forceinline__ float bf2f(u16 v){
  union { u32 u; float f; } c; c.u = ((u32)v) << 16; return c.f;
}

__device__ __forceinline__ u16 f2bf(float f){
  u32 u = __float_as_uint(f);
  u32 r = (u + 0x7FFFu + ((u >> 16) & 1u)) >> 16;   // round-to-nearest-even
  return (u16)r;
}

__device__ __forceinline__ uint4 pack8(float4 a, float4 b){
  union { uint4 v; u16 s[8]; } o;
  o.s[0]=f2bf(a.x); o.s[1]=f2bf(a.y); o.s[2]=f2bf(a.z); o.s[3]=f2bf(a.w);
  o.s[4]=f2bf(b.x); o.s[5]=f2bf(b.y); o.s[6]=f2bf(b.z); o.s[7]=f2bf(b.w);
  return o.v;
}

// ---------------- dtype detector: 1 wave, writes flag (1 = fp32 inputs) ----------------
__global__ __launch_bounds__(64) void k_detect(const u32* __restrict__ x, int* __restrict__ flag){
  int lane = threadIdx.x;
  int cnt = 0;
  for (int i = lane; i < 4096; i += 64){
    u32 w = x[i];
    int ex = (w >> 7) & 0xFF;
    cnt += (ex >= 140) ? 1 : 0;
  }
  #pragma unroll
  for (int off = 32; off; off >>= 1) cnt += __shfl_xor(cnt, off, 64);
  if (lane == 0) *flag = (cnt > 256) ? 1 : 0;
}

// ---------------- gate logits: (B,N,E) fp32 ----------------
__global__ __launch_bounds__(256) void k_logits(const void* __restrict__ xv, const void* __restrict__ gwv,
                                                const int* __restrict__ flag, float* __restrict__ logits){
  int is_f32 = *flag;
  int tid  = threadIdx.x;
  int wave = tid >> 6, lane = tid & 63;
  int token = (blockIdx.x << 2) + wave;
  float xf[16];
  float acc[8];
  #pragma unroll
  for (int e = 0; e < 8; e++) acc[e] = 0.f;

  if (is_f32){
    const float* xr = (const float*)xv + ((size_t)token << 10) + (lane << 4);
    #pragma unroll
    for (int q = 0; q < 4; q++){
      float4 v = *(const float4*)(xr + (q << 2));
      xf[q*4+0]=v.x; xf[q*4+1]=v.y; xf[q*4+2]=v.z; xf[q*4+3]=v.w;
    }
    const float* gw = (const float*)gwv;
    #pragma unroll
    for (int j = 0; j < 16; j++){
      const float* wr = gw + (((size_t)(lane << 4) + j) << 3);
      float4 w0 = *(const float4*)wr;
      float4 w1 = *(const float4*)(wr + 4);
      float xvv = xf[j];
      acc[0] += xvv*w0.x; acc[1] += xvv*w0.y; acc[2] += xvv*w0.z; acc[3] += xvv*w0.w;
      acc[4] += xvv*w1.x; acc[5] += xvv*w1.y; acc[6] += xvv*w1.z; acc[7] += xvv*w1.w;
    }
  } else {
    const u16* xr = (const u16*)xv + ((size_t)token << 10) + (lane << 4);
    union { uint4 v; u16 s[8]; } xa, xb;
    xa.v = *(const uint4*)xr;
    xb.v = *(const uint4*)(xr + 8);
    #pragma unroll
    for (int j = 0; j < 8; j++){ xf[j] = bf2f(xa.s[j]); xf[8 + j] = bf2f(xb.s[j]); }
    const u16* gw = (const u16*)gwv;
    #pragma unroll
    for (int j = 0; j < 16; j++){
      union { uint4 v; u16 s[8]; } wu;
      wu.v = *(const uint4*)(gw + (((lane << 4) + j) << 3));
      float xvv = xf[j];
      #pragma unroll
      for (int e = 0; e < 8; e++) acc[e] += xvv * bf2f(wu.s[e]);
    }
  }
  #pragma unroll
  for (int off = 32; off; off >>= 1){
    #pragma unroll
    for (int e = 0; e < 8; e++) acc[e] += __shfl_xor(acc[e], off, 64);
  }
  if (lane == 0){
    float4 a0 = make_float4(acc[0], acc[1], acc[2], acc[3]);
    float4 a1 = make_float4(acc[4], acc[5], acc[6], acc[7]);
    float* op = logits + ((size_t)token << 3);
    *(float4*)op = a0;
    *(float4*)(op + 4) = a1;
  }
}

// ---------------- fused: sinkhorn (blocks 0-3) + cvt_wt + cvt_x + zero (rest) ----------------
// Sinkhorn is LINEAR-DOMAIN (TEMPERATURE=1 makes log/exp cancel exactly):
//   M = clamp(g,1e-6); 8x { M /= colsum(M); M /= rowsum(M) }.
// No transcendentals, no max-stabilization (values provably bounded in fp32 range).
// State lives in L2 (128 KB/batch): each thread owns tokens {tid,+1024,+2048,+3072}
// exclusively, reloads per phase -> no 32-float register array -> no spills.
__global__ __launch_bounds__(1024) void k_fused(float* __restrict__ gates,
                                                const void* __restrict__ xv,
                                                const void* __restrict__ Wv,
                                                const int* __restrict__ flag,
                                                u16* __restrict__ xb,
                                                u16* __restrict__ WT,
                                                uint4* __restrict__ out,
                                                int out_size, int mode){
  __shared__ __align__(16) char smem[36864];   // cvt_wt: 4 x [64][72] u16 tiles; sinkhorn: 136 floats
  int bx = blockIdx.x;
  int tid = threadIdx.x;

  if (bx < 4){
    // ---- sinkhorn: batch = bx ----
    int wave = tid >> 6, lane = tid & 63;
    float* wred = (float*)smem;          // [16][8] cross-wave partial colsums
    float* lbc  = wred + 128;            // [8] inverse colsums broadcast
    float* gb = gates + ((size_t)bx << 15);

    for (int it = 0; it < 8; it++){
      // ---- phase A: column partial sums over my 4 tokens ----
      float s0=0,s1=0,s2=0,s3=0,s4=0,s5=0,s6=0,s7=0;
      #pragma unroll
      for (int q = 0; q < 4; q++){
        const float* gp = gb + (((q << 10) + tid) << 3);
        float4 a = *(const float4*)gp;
        float4 b = *(const float4*)(gp + 4);
        if (it == 0){
          a.x=fmaxf(a.x,1e-6f); a.y=fmaxf(a.y,1e-6f); a.z=fmaxf(a.z,1e-6f); a.w=fmaxf(a.w,1e-6f);
          b.x=fmaxf(b.x,1e-6f); b.y=fmaxf(b.y,1e-6f); b.z=fmaxf(b.z,1e-6f); b.w=fmaxf(b.w,1e-6f);
        }
        s0+=a.x; s1+=a.y; s2+=a.z; s3+=a.w; s4+=b.x; s5+=b.y; s6+=b.z; s7+=b.w;
      }
      float sa[8] = {s0,s1,s2,s3,s4,s5,s6,s7};
      #pragma unroll
      for (int e = 0; e < 8; e++){
        float v = sa[e];
        #pragma unroll
        for (int off = 32; off; off >>= 1) v += __shfl_xor(v, off, 64);
        if (lane == 0) wred[(wave << 3) + e] = v;
      }
      __syncthreads();
      if (tid < 8){
        float S = 0.f;
        #pragma unroll
        for (int w2 = 0; w2 < 16; w2++) S += wred[(w2 << 3) + tid];
        lbc[tid] = 1.0f / S;
      }
      __syncthreads();
      float ic0=lbc[0], ic1=lbc[1], ic2=lbc[2], ic3=lbc[3];
      float ic4=lbc[4], ic5=lbc[5], ic6=lbc[6], ic7=lbc[7];
      // ---- phase B: col-scale, local row-normalize, store ----
      #pragma unroll
      for (int q = 0; q < 4; q++){
        float* gp = gb + (((q << 10) + tid) << 3);
        float4 a = *(const float4*)gp;
        float4 b = *(const float4*)(gp + 4);
        if (it == 0){
          a.x=fmaxf(a.x,1e-6f); a.y=fmaxf(a.y,1e-6f); a.z=fmaxf(a.z,1e-6f); a.w=fmaxf(a.w,1e-6f);
          b.x=fmaxf(b.x,1e-6f); b.y=fmaxf(b.y,1e-6f); b.z=fmaxf(b.z,1e-6f); b.w=fmaxf(b.w,1e-6f);
        }
        a.x*=ic0; a.y*=ic1; a.z*=ic2; a.w*=ic3;
        b.x*=ic4; b.y*=ic5; b.z*=ic6; b.w*=ic7;
        float rs = ((a.x+a.y)+(a.z+a.w)) + ((b.x+b.y)+(b.z+b.w));
        float ir = 1.0f / rs;
        a.x*=ir; a.y*=ir; a.z*=ir; a.w*=ir;
        b.x*=ir; b.y*=ir; b.z*=ir; b.w*=ir;
        *(float4*)gp = a;
        *(float4*)(gp + 4) = b;
      }
      // no trailing sync needed: each thread exclusively owns its 4 token rows;
      // wred/lbc hazards are covered by the two syncs above (see ownership analysis).
    }
    return;
  }

  if (mode == 0){
    // fallback: bx 4..515 zero-fill
    int is_f32 = *flag;
    int rb = bx - 4;
    size_t words = (size_t)out_size >> (is_f32 ? 0 : 1);
    size_t n4 = words >> 2;
    size_t i = (size_t)rb * 1024 + tid;
    uint4 z = make_uint4(0, 0, 0, 0);
    for (; i < n4; i += (size_t)512 * 1024) out[i] = z;
    return;
  }

  if (bx < 516){
    // ---- W (e,d,f) -> WT (e,f,d) bf16: 4 64x64 tiles per block ----
    int is_f32 = *flag;
    int rb = bx - 4;
    int sub = tid >> 8;
    int t = tid & 255;
    int g = (rb << 2) + sub;          // global tile id 0..2047
    int e = g >> 8, t2 = g & 255;
    int td = (t2 >> 4) << 6, tf = (t2 & 15) << 6;
    u16 (*tile)[72] = (u16(*)[72])(smem + (size_t)sub * (64 * 72 * 2));
    #pragma unroll
    for (int i = 0; i < 2; i++){
      int id = t + (i << 8);
      int row = id >> 3, c8 = id & 7;
      size_t src = ((size_t)(e*1024 + td + row))*1024 + tf + (c8 << 3);
      uint4 v;
      if (is_f32){
        const float* wf = (const float*)Wv;
        v = pack8(*(const float4*)(wf + src), *(const float4*)(wf + src + 4));
      } else {
        v = *(const uint4*)((const u16*)Wv + src);
      }
      *(uint4*)&tile[row][c8 << 3] = v;
    }
    __syncthreads();
    #pragma unroll
    for (int i = 0; i < 2; i++){
      int id = t + (i << 8);
      int frow = id >> 3, c8 = id & 7;
      union { uint4 v; u16 s[8]; } o;
      #pragma unroll
      for (int j = 0; j < 8; j++) o.s[j] = tile[(c8 << 3) + j][frow];
      *(uint4*)(WT + ((size_t)(e*1024 + tf + frow))*1024 + td + (c8 << 3)) = o.v;
    }
    return;
  }

  if (bx < 2564){
    // ---- x -> bf16 copy/convert ----
    int is_f32 = *flag;
    int rb = bx - 516;
    size_t base = ((size_t)rb * 1024 + tid) << 3;
    if (is_f32){
      const float* xf = (const float*)xv;
      float4 a = *(const float4*)(xf + base);
      float4 b = *(const float4*)(xf + base + 4);
      *(uint4*)(xb + base) = pack8(a, b);
    } else {
      *(uint4*)(xb + base) = *(const uint4*)((const u16*)xv + base);
    }
    return;
  }

  {
    // ---- zero-fill d_out ----
    int is_f32 = *flag;
    int rb = bx - 2564;
    size_t words = (size_t)out_size >> (is_f32 ? 0 : 1);
    size_t n4 = words >> 2;
    size_t i = (size_t)rb * 1024 + tid;
    uint4 z = make_uint4(0, 0, 0, 0);
    for (; i < n4; i += (size_t)512 * 1024) out[i] = z;
  }
}

// ---------------- top-512 via exact rank-by-counting, v2 ----------------
// rank(i) = #{j<i: v_j >= v_i} + #{j>i: v_j > v_i}  == jax top_k order, single compare per pair.
// Grid: 1024 blocks = 32 (b,e)-columns x 32 slices of 128 tokens. Block: 256 threads.
__global__ __launch_bounds__(256) void k_rank(const float* __restrict__ gates,
                                              int* __restrict__ routed, int* __restrict__ winner){
  __shared__ u32 ord_s[4096];
  __shared__ u32 cnt_s[1024];    // [js][local_token]
  int bx = blockIdx.x;
  int be = bx >> 5;              // 0..31
  int b = be >> 3, e = be & 7;
  int slice = bx & 31;           // 0..31
  int tid = threadIdx.x;
  const float* gb = gates + (size_t)b * (4096 * 8);
  for (int i = tid; i < 4096; i += 256){
    float v = gb[(i << 3) + e];
    u32 fb = __float_as_uint(v);
    ord_s[i] = fb ^ ((fb >> 31) ? 0xFFFFFFFFu : 0x80000000u);   // monotone total order
  }
  __syncthreads();

  int tg = tid & 31;             // token group: 4 tokens
  int js = tid >> 5;             // j-slice: 0..7, 512 j's each
  int i0 = (slice << 7) + (tg << 2);          // first of my 4 tokens (4-aligned)
  int gchunk = i0 & ~7;                       // the 8-chunk containing all 4 tokens
  u32 v0 = ord_s[i0], v1 = ord_s[i0+1], v2 = ord_s[i0+2], v3 = ord_s[i0+3];
  int jlo = js << 9, jhi = jlo + 512;
  int c0 = 0, c1 = 0, c2 = 0, c3 = 0;

  // span A: chunks entirely below gchunk -> predicate >=
  int endA = min(jhi, gchunk);
  for (int j = jlo; j < endA; j += 8){
    uint4 w0 = *(const uint4*)&ord_s[j];
    uint4 w1 = *(const uint4*)&ord_s[j + 4];
    c0 += (w0.x>=v0)+(w0.y>=v0)+(w0.z>=v0)+(w0.w>=v0)+(w1.x>=v0)+(w1.y>=v0)+(w1.z>=v0)+(w1.w>=v0);
    c1 += (w0.x>=v1)+(w0.y>=v1)+(w0.z>=v1)+(w0.w>=v1)+(w1.x>=v1)+(w1.y>=v1)+(w1.z>=v1)+(w1.w>=v1);
    c2 += (w0.x>=v2)+(w0.y>=v2)+(w0.z>=v2)+(w0.w>=v2)+(w1.x>=v2)+(w1.y>=v2)+(w1.z>=v2)+(w1.w>=v2);
    c3 += (w0.x>=v3)+(w0.y>=v3)+(w0.z>=v3)+(w0.w>=v3)+(w1.x>=v3)+(w1.y>=v3)+(w1.z>=v3)+(w1.w>=v3);
  }
  // span B: chunks entirely above gchunk -> predicate >
  int begB = max(jlo, gchunk + 8);
  for (int j = begB; j < jhi; j += 8){
    uint4 w0 = *(const uint4*)&ord_s[j];
    uint4 w1 = *(const uint4*)&ord_s[j + 4];
    c0 += (w0.x>v0)+(w0.y>v0)+(w0.z>v0)+(w0.w>v0)+(w1.x>v0)+(w1.y>v0)+(w1.z>v0)+(w1.w>v0);
    c1 += (w0.x>v1)+(w0.y>v1)+(w0.z>v1)+(w0.w>v1)+(w1.x>v1)+(w1.y>v1)+(w1.z>v1)+(w1.w>v1);
    c2 += (w0.x>v2)+(w0.y>v2)+(w0.z>v2)+(w0.w>v2)+(w1.x>v2)+(w1.y>v2)+(w1.z>v2)+(w1.w>v2);
    c3 += (w0.x>v3)+(w0.y>v3)+(w0.z>v3)+(w0.w>v3)+(w1.x>v3)+(w1.y>v3)+(w1.z>v3)+(w1.w>v3);
  }
  // boundary chunk (contains my 4 tokens) — element-wise j<i test
  if (gchunk >= jlo && gchunk < jhi){
    int base_off = i0 & 7;       // i0 - gchunk: 0 or 4
    #pragma unroll
    for (int jj = 0; jj < 8; jj++){
      u32 w = ord_s[gchunk + jj];
      c0 += (jj < base_off + 0) ? (w >= v0) : (w > v0);
      c1 += (jj < base_off + 1) ? (w >= v1) : (w > v1);
      c2 += (jj < base_off + 2) ? (w >= v2) : (w > v2);
      c3 += (jj < base_off + 3) ? (w >= v3) : (w > v3);
    }
  }
  int lt = tg << 2;              // local token base
  cnt_s[(js << 7) + lt + 0] = c0;
  cnt_s[(js << 7) + lt + 1] = c1;
  cnt_s[(js << 7) + lt + 2] = c2;
  cnt_s[(js << 7) + lt + 3] = c3;
  __syncthreads();
  if (tid < 128){
    int rank = 0;
    #pragma unroll
    for (int s = 0; s < 8; s++) rank += cnt_s[(s << 7) + tid];
    int i = (slice << 7) + tid;
    if (rank < 512){
      routed[(be << 9) + rank] = i;
      atomicMax(&winner[(b << 12) + i], (rank << 3) | e);   // numpy last-write-wins: max (m,e)
    }
  }
}

// ---------------- fast gathered GEMM: pre-converted bf16 x and (e,f,d) WT ----------------
__global__ __launch_bounds__(256) void k_gemm_fast(const u16* __restrict__ xb, const u16* __restrict__ WT,
                                                   const float* __restrict__ gates,
                                                   const int* __restrict__ routed,
                                                   const int* __restrict__ winner,
                                                   const int* __restrict__ flag,
                                                   void* __restrict__ outv){
  __shared__ u16 As[128 * 32];
  __shared__ u16 Bs[128 * 32];
  __shared__ int   tok_s[128];
  __shared__ float gate_s[128];
  __shared__ int   flg_s[128];
  int is_f32 = *flag;
  int bx = blockIdx.x;
  int gemm = bx >> 5, tile = bx & 31;
  int b = gemm >> 3, e = gemm & 7;
  int mt = tile & 3, nt = tile >> 2;
  int tid = threadIdx.x;
  int w = tid >> 6, lane = tid & 63;
  int quad = lane >> 4, l16 = lane & 15;

  const int* idx_base = routed + (((b << 3) + e) << 9) + (mt << 7);

  if (tid < 128){
    int tok = idx_base[tid];
    int mg  = (mt << 7) + tid;
    int win = winner[(b << 12) + tok];
    tok_s[tid]  = tok;
    flg_s[tid]  = (win == ((mg << 3) | e)) ? 1 : 0;
    gate_s[tid] = gates[((((size_t)b << 12) + tok) << 3) + e];
  }
  __syncthreads();

  int r0 = tid >> 2;
  int ch = tid & 3;
  int r1 = r0 + 64;
  const u16* gA0 = xb + ((((size_t)b << 12) + tok_s[r0]) << 10) + (ch << 3);
  const u16* gA1 = xb + ((((size_t)b << 12) + tok_s[r1]) << 10) + (ch << 3);
  int f0 = nt << 7;
  const u16* gB0 = WT + ((((size_t)e << 10) + f0 + r0) << 10) + (ch << 3);
  const u16* gB1 = WT + ((((size_t)e << 10) + f0 + r1) << 10) + (ch << 3);

  f32x4 acc[4][4] = {};
  int wm = (w & 1) << 6, wn = (w >> 1) << 6;

  for (int k0 = 0; k0 < 1024; k0 += 32){
    uint4 a0 = *(const uint4*)(gA0 + k0);
    uint4 a1 = *(const uint4*)(gA1 + k0);
    uint4 b0 = *(const uint4*)(gB0 + k0);
    uint4 b1 = *(const uint4*)(gB1 + k0);
    *(uint4*)&As[(r0 << 5) + (ch << 3)] = a0;
    *(uint4*)&As[(r1 << 5) + (ch << 3)] = a1;
    *(uint4*)&Bs[(r0 << 5) + (ch << 3)] = b0;
    *(uint4*)&Bs[(r1 << 5) + (ch << 3)] = b1;
    __syncthreads();
    s16x8 af[4], bv[4];
    #pragma unroll
    for (int im = 0; im < 4; im++)
      af[im] = *(const s16x8*)&As[((wm + (im << 4) + l16) << 5) + (quad << 3)];
    #pragma unroll
    for (int in = 0; in < 4; in++)
      bv[in] = *(const s16x8*)&Bs[((wn + (in << 4) + l16) << 5) + (quad << 3)];
    __syncthreads();
    #pragma unroll
    for (int im = 0; im < 4; im++){
      #pragma unroll
      for (int in = 0; in < 4; in++)
        acc[im][in] = __builtin_amdgcn_mfma_f32_16x16x32_bf16(af[im], bv[in], acc[im][in], 0, 0, 0);
    }
  }

  #pragma unroll
  for (int im = 0; im < 4; im++){
    #pragma unroll
    for (int r = 0; r < 4; r++){
      int mrow = wm + (im << 4) + (quad << 2) + r;
      if (flg_s[mrow]){
        float g  = gate_s[mrow];
        int tok  = tok_s[mrow];
        size_t obase = ((((size_t)b << 12) + tok) << 10) + f0 + wn + l16;
        if (is_f32){
          float* o32 = (float*)outv;
          #pragma unroll
          for (int in = 0; in < 4; in++) o32[obase + (in << 4)] = acc[im][in][r] * g;
        } else {
          u16* o16 = (u16*)outv;
          #pragma unroll
          for (int in = 0; in < 4; in++) o16[obase + (in << 4)] = f2bf(acc[im][in][r] * g);
        }
      }
    }
  }
}

// ---------------- fallback GEMM (round-4 validated): on-the-fly convert + LDS transpose ----------------
__global__ __launch_bounds__(256) void k_gemm_slow(const void* __restrict__ xv, const void* __restrict__ Wv,
                                                   const float* __restrict__ gates,
                                                   const int* __restrict__ routed,
                                                   const int* __restrict__ winner,
                                                   const int* __restrict__ flag,
                                                   void* __restrict__ outv){
  __shared__ u16 As[128 * 32];
  __shared__ u16 Bw[32 * 132];
  __shared__ u16 Bs[128 * 32];
  __shared__ int   tok_s[128];
  __shared__ float gate_s[128];
  __shared__ int   flg_s[128];
  int is_f32 = *flag;
  int bx = blockIdx.x;
  int gemm = bx >> 5, tile = bx & 31;
  int b = gemm >> 3, e = gemm & 7;
  int mt = tile & 3, nt = tile >> 2;
  int tid = threadIdx.x;
  int w = tid >> 6, lane = tid & 63;
  int quad = lane >> 4, l16 = lane & 15;

  const int* idx_base = routed + (((b << 3) + e) << 9) + (mt << 7);

  if (tid < 128){
    int tok = idx_base[tid];
    int mg  = (mt << 7) + tid;
    int win = winner[(b << 12) + tok];
    tok_s[tid]  = tok;
    flg_s[tid]  = (win == ((mg << 3) | e)) ? 1 : 0;
    gate_s[tid] = gates[((((size_t)b << 12) + tok) << 3) + e];
  }
  __syncthreads();

  int r0 = tid >> 2;
  int ch = tid & 3;
  int r1 = r0 + 64;
  size_t offA0 = ((((size_t)b << 12) + tok_s[r0]) << 10) + (ch << 3);
  size_t offA1 = ((((size_t)b << 12) + tok_s[r1]) << 10) + (ch << 3);
  int f0 = nt << 7;
  int kkB0 = tid >> 4;
  int fcB  = tid & 15;
  size_t offB0 = ((size_t)e << 20) + ((size_t)kkB0 << 10) + f0 + (fcB << 3);
  size_t offB1 = offB0 + ((size_t)16 << 10);
  int f_loc = tid >> 1;
  int half  = tid & 1;

  f32x4 acc[4][4] = {};
  int wm = (w & 1) << 6, wn = (w >> 1) << 6;

  for (int k0 = 0; k0 < 1024; k0 += 32){
    uint4 a0, a1, b0, b1;
    if (is_f32){
      const float* xf = (const float*)xv;
      const float* wf = (const float*)Wv;
      a0 = pack8(*(const float4*)(xf + offA0 + k0), *(const float4*)(xf + offA0 + k0 + 4));
      a1 = pack8(*(const float4*)(xf + offA1 + k0), *(const float4*)(xf + offA1 + k0 + 4));
      b0 = pack8(*(const float4*)(wf + offB0 + ((size_t)k0 << 10)),
                 *(const float4*)(wf + offB0 + ((size_t)k0 << 10) + 4));
      b1 = pack8(*(const float4*)(wf + offB1 + ((size_t)k0 << 10)),
                 *(const float4*)(wf + offB1 + ((size_t)k0 << 10) + 4));
    } else {
      const u16* xh = (const u16*)xv;
      const u16* wh = (const u16*)Wv;
      a0 = *(const uint4*)(xh + offA0 + k0);
      a1 = *(const uint4*)(xh + offA1 + k0);
      b0 = *(const uint4*)(wh + offB0 + ((size_t)k0 << 10));
      b1 = *(const uint4*)(wh + offB1 + ((size_t)k0 << 10));
    }
    *(uint4*)&As[(r0 << 5) + (ch << 3)] = a0;
    *(uint4*)&As[(r1 << 5) + (ch << 3)] = a1;
    *(uint4*)&Bw[kkB0 * 132 + (fcB << 3)] = b0;
    *(uint4*)&Bw[(kkB0 + 16) * 132 + (fcB << 3)] = b1;
    __syncthreads();
    union { uint4 v[2]; u16 s[16]; } tv;
    #pragma unroll
    for (int j = 0; j < 16; j++) tv.s[j] = Bw[((half << 4) + j) * 132 + f_loc];
    *(uint4*)&Bs[(f_loc << 5) + (half << 4)]     = tv.v[0];
    *(uint4*)&Bs[(f_loc << 5) + (half << 4) + 8] = tv.v[1];
    __syncthreads();
    s16x8 af[4], bv[4];
    #pragma unroll
    for (int im = 0; im < 4; im++)
      af[im] = *(const s16x8*)&As[((wm + (im << 4) + l16) << 5) + (quad << 3)];
    #pragma unroll
    for (int in = 0; in < 4; in++)
      bv[in] = *(const s16x8*)&Bs[((wn + (in << 4) + l16) << 5) + (quad << 3)];
    __syncthreads();
    #pragma unroll
    for (int im = 0; im < 4; im++){
      #pragma unroll
      for (int in = 0; in < 4; in++)
        acc[im][in] = __builtin_amdgcn_mfma_f32_16x16x32_bf16(af[im], bv[in], acc[im][in], 0, 0, 0);
    }
  }

  #pragma unroll
  for (int im = 0; im < 4; im++){
    #pragma unroll
    for (int r = 0; r < 4; r++){
      int mrow = wm + (im << 4) + (quad << 2) + r;
      if (flg_s[mrow]){
        float g  = gate_s[mrow];
        int tok  = tok_s[mrow];
        size_t obase = ((((size_t)b << 12) + tok) << 10) + f0 + wn + l16;
        if (is_f32){
          float* o32 = (float*)outv;
          #pragma unroll
          for (int in = 0; in < 4; in++) o32[obase + (in << 4)] = acc[im][in][r] * g;
        } else {
          u16* o16 = (u16*)outv;
          #pragma unroll
          for (int in = 0; in < 4; in++) o16[obase + (in << 4)] = f2bf(acc[im][in][r] * g);
        }
      }
    }
  }
}

extern "C" void kernel_launch(void* const* d_in, const int* in_sizes, int n_in,
                              void* d_out, int out_size, void* d_ws, size_t ws_size,
                              hipStream_t stream){
  const void* x  = d_in[0];   // (4,4096,1024)
  const void* gw = d_in[1];   // (1024,8)
  const void* W  = d_in[2];   // (8,1024,1024)
  char* ws = (char*)d_ws;
  float* gates  = (float*)ws;                               // 524288 B
  int*   winner = (int*)(ws + 524288);                      // 65536 B
  int*   routed = (int*)(ws + 589824);                      // 65536 B
  int*   flag   = (int*)(ws + 655360);                      // 256 B (padded)
  u16*   xb     = (u16*)(ws + 655616);                      // 33554432 B
  u16*   WT     = (u16*)(ws + 655616 + 33554432);           // 16777216 B
  size_t need_fast = 655616ull + 33554432ull + 16777216ull; // ~48.6 MiB
  bool fast = ws_size >= need_fast;

  hipMemsetAsync(winner, 0xFF, 65536, stream);
  hipLaunchKernelGGL(k_detect,   dim3(1),    dim3(64),   0, stream, (const u32*)x, flag);
  hipLaunchKernelGGL(k_logits,   dim3(4096), dim3(256),  0, stream, x, gw, flag, gates);
  if (fast){
    hipLaunchKernelGGL(k_fused, dim3(3076), dim3(1024), 0, stream,
                       gates, x, W, flag, xb, WT, (uint4*)d_out, out_size, 1);
    hipLaunchKernelGGL(k_rank,  dim3(1024), dim3(256),  0, stream, gates, routed, winner);
    hipLaunchKernelGGL(k_gemm_fast, dim3(1024), dim3(256), 0, stream, xb, WT, gates, routed, winner,
                       flag, d_out);
  } else {
    hipLaunchKernelGGL(k_fused, dim3(516), dim3(1024), 0, stream,
                       gates, x, W, flag, xb, WT, (uint4*)d_out, out_size, 0);
    hipLaunchKernelGGL(k_rank,  dim3(1024), dim3(256),  0, stream, gates, routed, winner);
    hipLaunchKernelGGL(k_gemm_slow, dim3(1024), dim3(256), 0, stream, x, W, gates, routed, winner,
                       flag, d_out);
  }
}

// Round 4
// 288.423 us; speedup vs baseline: 1.7844x; 1.2804x over previous
//
#include <hip/hip_runtime.h>
#include <hip/hip_bf16.h>
#include <stdint.h>

typedef short s16x8 __attribute__((ext_vector_type(8)));
typedef float f32x4 __attribute__((ext_vector_type(4)));
typedef unsigned short u16;
typedef unsigned int u32;
typedef unsigned long long u64;

__device__ __forceinline__ float bf2f(u16 v){
  union { u32 u; float f; } c; c.u = ((u32)v) << 16; return c.f;
}

__device__ __forceinline__ u16 f2bf(float f){
  u32 u = __float_as_uint(f);
  u32 r = (u + 0x7FFFu + ((u >> 16) & 1u)) >> 16;   // round-to-nearest-even
  return (u16)r;
}

__device__ __forceinline__ uint4 pack8(float4 a, float4 b){
  union { uint4 v; u16 s[8]; } o;
  o.s[0]=f2bf(a.x); o.s[1]=f2bf(a.y); o.s[2]=f2bf(a.z); o.s[3]=f2bf(a.w);
  o.s[4]=f2bf(b.x); o.s[5]=f2bf(b.y); o.s[6]=f2bf(b.z); o.s[7]=f2bf(b.w);
  return o.v;
}

// ---------------- dtype detector: 1 wave, writes flag (1 = fp32 inputs) ----------------
__global__ __launch_bounds__(64) void k_detect(const u32* __restrict__ x, int* __restrict__ flag){
  int lane = threadIdx.x;
  int cnt = 0;
  for (int i = lane; i < 4096; i += 64){
    u32 w = x[i];
    int ex = (w >> 7) & 0xFF;
    cnt += (ex >= 140) ? 1 : 0;
  }
  #pragma unroll
  for (int off = 32; off; off >>= 1) cnt += __shfl_xor(cnt, off, 64);
  if (lane == 0) *flag = (cnt > 256) ? 1 : 0;
}

// ---------------- fused logits + x->bf16 convert ----------------
// 2048 blocks x 1024 threads; block handles 8 tokens (8192 elements of x).
// Thread t: token tl=t>>7, pos=t&127, loads 8 CONSECUTIVE floats (coalesced),
// writes xb, and computes partial dot with gw rows pos*8..pos*8+7 read from a
// chunk-XOR-swizzled LDS copy of gw (conflict-free ds_read_b128).
// gw_swz[p][c] stored at p*16 + (c ^ (p&15)); involution on read.
__global__ __launch_bounds__(1024) void k_logits_cvt(const void* __restrict__ xv,
                                                     const void* __restrict__ gwv,
                                                     const int* __restrict__ flag,
                                                     u16* __restrict__ xb,
                                                     float* __restrict__ gates,
                                                     int mode){
  __shared__ float4 gw_swz[2048];   // 32 KB: [p 0..127][c 0..15] swizzled
  __shared__ float  wacc[16][8];
  int is_f32 = *flag;
  int tid = threadIdx.x;

  // ---- stage gw (1024 rows, one per thread), swizzled ----
  {
    int r = tid;
    float g0,g1,g2,g3,g4,g5,g6,g7;
    if (is_f32){
      const float* gw = (const float*)gwv + ((size_t)r << 3);
      float4 u = *(const float4*)gw;
      float4 v = *(const float4*)(gw + 4);
      g0=u.x; g1=u.y; g2=u.z; g3=u.w; g4=v.x; g5=v.y; g6=v.z; g7=v.w;
    } else {
      union { uint4 v; u16 s[8]; } wu;
      wu.v = *(const uint4*)((const u16*)gwv + ((size_t)r << 3));
      g0=bf2f(wu.s[0]); g1=bf2f(wu.s[1]); g2=bf2f(wu.s[2]); g3=bf2f(wu.s[3]);
      g4=bf2f(wu.s[4]); g5=bf2f(wu.s[5]); g6=bf2f(wu.s[6]); g7=bf2f(wu.s[7]);
    }
    int p = r >> 3, j = r & 7;
    gw_swz[(p << 4) + (((j << 1)    ) ^ (p & 15))] = make_float4(g0,g1,g2,g3);
    gw_swz[(p << 4) + (((j << 1) | 1) ^ (p & 15))] = make_float4(g4,g5,g6,g7);
  }

  // ---- load x (8 consecutive floats), write xb ----
  int tl = tid >> 7, pos = tid & 127;
  size_t base = ((((size_t)blockIdx.x << 3) + tl) << 10) + ((size_t)pos << 3);
  float xf[8];
  if (is_f32){
    const float* xr = (const float*)xv + base;
    float4 u = *(const float4*)xr;
    float4 v = *(const float4*)(xr + 4);
    xf[0]=u.x; xf[1]=u.y; xf[2]=u.z; xf[3]=u.w;
    xf[4]=v.x; xf[5]=v.y; xf[6]=v.z; xf[7]=v.w;
    if (mode) *(uint4*)(xb + base) = pack8(u, v);
  } else {
    uint4 raw = *(const uint4*)((const u16*)xv + base);
    union { uint4 v; u16 s[8]; } xu; xu.v = raw;
    #pragma unroll
    for (int k = 0; k < 8; k++) xf[k] = bf2f(xu.s[k]);
    if (mode) *(uint4*)(xb + base) = raw;
  }
  __syncthreads();

  // ---- dot: acc[e] = sum_j xf[j] * gw[pos*8+j][e] ----
  float a0=0,a1=0,a2=0,a3=0,a4=0,a5=0,a6=0,a7=0;
  #pragma unroll
  for (int j = 0; j < 8; j++){
    float4 wA = gw_swz[(pos << 4) + (((j << 1)    ) ^ (pos & 15))];
    float4 wB = gw_swz[(pos << 4) + (((j << 1) | 1) ^ (pos & 15))];
    float xv8 = xf[j];
    a0 += xv8*wA.x; a1 += xv8*wA.y; a2 += xv8*wA.z; a3 += xv8*wA.w;
    a4 += xv8*wB.x; a5 += xv8*wB.y; a6 += xv8*wB.z; a7 += xv8*wB.w;
  }
  #pragma unroll
  for (int off = 32; off; off >>= 1){
    a0 += __shfl_xor(a0, off, 64); a1 += __shfl_xor(a1, off, 64);
    a2 += __shfl_xor(a2, off, 64); a3 += __shfl_xor(a3, off, 64);
    a4 += __shfl_xor(a4, off, 64); a5 += __shfl_xor(a5, off, 64);
    a6 += __shfl_xor(a6, off, 64); a7 += __shfl_xor(a7, off, 64);
  }
  int wave = tid >> 6, lane = tid & 63;
  if (lane == 0){
    wacc[wave][0]=a0; wacc[wave][1]=a1; wacc[wave][2]=a2; wacc[wave][3]=a3;
    wacc[wave][4]=a4; wacc[wave][5]=a5; wacc[wave][6]=a6; wacc[wave][7]=a7;
  }
  __syncthreads();
  if (tid < 64){
    int tt = tid >> 3, e = tid & 7;
    float v = wacc[(tt << 1)][e] + wacc[(tt << 1) | 1][e];
    gates[((((size_t)blockIdx.x << 3) + tt) << 3) + e] = v;
  }
}

// ---------------- fused: sinkhorn (blocks 0-3) + cvt_wt + zero cover ----------------
// Sinkhorn linear-domain, REGISTER-RESIDENT: thread owns tokens {tid,+1024,+2048,+3072}
// as float4 va[4] (e0-3) / vb[4] (e4-7), all statically indexed. One load, 8 pure-VALU
// iterations (1 sum-reduce each), one store. ~3 us, hidden under the BW roles.
// mode==1: bx 0..3 sinkhorn, 4..515 W->WT transpose, 516..1027 zero d_out.
// mode==0: bx 0..3 sinkhorn, 4..515 zero d_out.
__global__ __launch_bounds__(1024) void k_sink_cover(float* __restrict__ gates,
                                                     const void* __restrict__ Wv,
                                                     const int* __restrict__ flag,
                                                     u16* __restrict__ WT,
                                                     uint4* __restrict__ out,
                                                     int out_size, int mode){
  __shared__ __align__(16) char smem[36864];
  int bx = blockIdx.x;
  int tid = threadIdx.x;

  if (bx < 4){
    float* wred = (float*)smem;      // [16][8]
    float* lbc  = wred + 128;        // [8]
    int wave = tid >> 6, lane = tid & 63;
    float* gb = gates + ((size_t)bx << 15);
    float4 va[4], vb[4];
    #pragma unroll
    for (int q = 0; q < 4; q++){
      float* gp = gb + (((q << 10) + tid) << 3);
      float4 a = *(const float4*)gp;
      float4 b = *(const float4*)(gp + 4);
      a.x=fmaxf(a.x,1e-6f); a.y=fmaxf(a.y,1e-6f); a.z=fmaxf(a.z,1e-6f); a.w=fmaxf(a.w,1e-6f);
      b.x=fmaxf(b.x,1e-6f); b.y=fmaxf(b.y,1e-6f); b.z=fmaxf(b.z,1e-6f); b.w=fmaxf(b.w,1e-6f);
      va[q]=a; vb[q]=b;
    }
    for (int it = 0; it < 8; it++){
      float s0 = ((va[0].x+va[1].x)+(va[2].x+va[3].x));
      float s1 = ((va[0].y+va[1].y)+(va[2].y+va[3].y));
      float s2 = ((va[0].z+va[1].z)+(va[2].z+va[3].z));
      float s3 = ((va[0].w+va[1].w)+(va[2].w+va[3].w));
      float s4 = ((vb[0].x+vb[1].x)+(vb[2].x+vb[3].x));
      float s5 = ((vb[0].y+vb[1].y)+(vb[2].y+vb[3].y));
      float s6 = ((vb[0].z+vb[1].z)+(vb[2].z+vb[3].z));
      float s7 = ((vb[0].w+vb[1].w)+(vb[2].w+vb[3].w));
      #pragma unroll
      for (int off = 32; off; off >>= 1){
        s0 += __shfl_xor(s0, off, 64); s1 += __shfl_xor(s1, off, 64);
        s2 += __shfl_xor(s2, off, 64); s3 += __shfl_xor(s3, off, 64);
        s4 += __shfl_xor(s4, off, 64); s5 += __shfl_xor(s5, off, 64);
        s6 += __shfl_xor(s6, off, 64); s7 += __shfl_xor(s7, off, 64);
      }
      if (lane == 0){
        wred[(wave<<3)+0]=s0; wred[(wave<<3)+1]=s1; wred[(wave<<3)+2]=s2; wred[(wave<<3)+3]=s3;
        wred[(wave<<3)+4]=s4; wred[(wave<<3)+5]=s5; wred[(wave<<3)+6]=s6; wred[(wave<<3)+7]=s7;
      }
      __syncthreads();
      if (tid < 8){
        float S = 0.f;
        #pragma unroll
        for (int w2 = 0; w2 < 16; w2++) S += wred[(w2 << 3) + tid];
        lbc[tid] = 1.0f / S;
      }
      __syncthreads();
      float i0=lbc[0], i1=lbc[1], i2=lbc[2], i3=lbc[3];
      float i4=lbc[4], i5=lbc[5], i6=lbc[6], i7=lbc[7];
      #pragma unroll
      for (int q = 0; q < 4; q++){
        float4 a = va[q], b = vb[q];
        a.x*=i0; a.y*=i1; a.z*=i2; a.w*=i3;
        b.x*=i4; b.y*=i5; b.z*=i6; b.w*=i7;
        float rs = ((a.x+a.y)+(a.z+a.w)) + ((b.x+b.y)+(b.z+b.w));
        float ir = 1.0f / rs;
        a.x*=ir; a.y*=ir; a.z*=ir; a.w*=ir;
        b.x*=ir; b.y*=ir; b.z*=ir; b.w*=ir;
        va[q]=a; vb[q]=b;
      }
    }
    #pragma unroll
    for (int q = 0; q < 4; q++){
      float* gp = gb + (((q << 10) + tid) << 3);
      *(float4*)gp = va[q];
      *(float4*)(gp + 4) = vb[q];
    }
    return;
  }

  if (mode == 0){
    int is_f32 = *flag;
    int rb = bx - 4;
    size_t words = (size_t)out_size >> (is_f32 ? 0 : 1);
    size_t n4 = words >> 2;
    size_t i = (size_t)rb * 1024 + tid;
    uint4 z = make_uint4(0, 0, 0, 0);
    for (; i < n4; i += (size_t)512 * 1024) out[i] = z;
    return;
  }

  if (bx < 516){
    // ---- W (e,d,f) -> WT (e,f,d) bf16: 4 64x64 tiles per block ----
    int is_f32 = *flag;
    int rb = bx - 4;
    int sub = tid >> 8;
    int t = tid & 255;
    int g = (rb << 2) + sub;          // global tile id 0..2047
    int e = g >> 8, t2 = g & 255;
    int td = (t2 >> 4) << 6, tf = (t2 & 15) << 6;
    u16 (*tile)[72] = (u16(*)[72])(smem + (size_t)sub * (64 * 72 * 2));
    #pragma unroll
    for (int i = 0; i < 2; i++){
      int id = t + (i << 8);
      int row = id >> 3, c8 = id & 7;
      size_t src = ((size_t)(e*1024 + td + row))*1024 + tf + (c8 << 3);
      uint4 v;
      if (is_f32){
        const float* wf = (const float*)Wv;
        v = pack8(*(const float4*)(wf + src), *(const float4*)(wf + src + 4));
      } else {
        v = *(const uint4*)((const u16*)Wv + src);
      }
      *(uint4*)&tile[row][c8 << 3] = v;
    }
    __syncthreads();
    #pragma unroll
    for (int i = 0; i < 2; i++){
      int id = t + (i << 8);
      int frow = id >> 3, c8 = id & 7;
      union { uint4 v; u16 s[8]; } o;
      #pragma unroll
      for (int j = 0; j < 8; j++) o.s[j] = tile[(c8 << 3) + j][frow];
      *(uint4*)(WT + ((size_t)(e*1024 + tf + frow))*1024 + td + (c8 << 3)) = o.v;
    }
    return;
  }

  {
    // ---- zero-fill d_out ----
    int is_f32 = *flag;
    int rb = bx - 516;
    size_t words = (size_t)out_size >> (is_f32 ? 0 : 1);
    size_t n4 = words >> 2;
    size_t i = (size_t)rb * 1024 + tid;
    uint4 z = make_uint4(0, 0, 0, 0);
    for (; i < n4; i += (size_t)512 * 1024) out[i] = z;
  }
}

// ---------------- top-512 via exact rank-by-counting, v2 ----------------
__global__ __launch_bounds__(256) void k_rank(const float* __restrict__ gates,
                                              int* __restrict__ routed, int* __restrict__ winner){
  __shared__ u32 ord_s[4096];
  __shared__ u32 cnt_s[1024];    // [js][local_token]
  int bx = blockIdx.x;
  int be = bx >> 5;              // 0..31
  int b = be >> 3, e = be & 7;
  int slice = bx & 31;           // 0..31
  int tid = threadIdx.x;
  const float* gb = gates + (size_t)b * (4096 * 8);
  for (int i = tid; i < 4096; i += 256){
    float v = gb[(i << 3) + e];
    u32 fb = __float_as_uint(v);
    ord_s[i] = fb ^ ((fb >> 31) ? 0xFFFFFFFFu : 0x80000000u);   // monotone total order
  }
  __syncthreads();

  int tg = tid & 31;             // token group: 4 tokens
  int js = tid >> 5;             // j-slice: 0..7, 512 j's each
  int i0 = (slice << 7) + (tg << 2);          // first of my 4 tokens (4-aligned)
  int gchunk = i0 & ~7;                       // the 8-chunk containing all 4 tokens
  u32 v0 = ord_s[i0], v1 = ord_s[i0+1], v2 = ord_s[i0+2], v3 = ord_s[i0+3];
  int jlo = js << 9, jhi = jlo + 512;
  int c0 = 0, c1 = 0, c2 = 0, c3 = 0;

  int endA = min(jhi, gchunk);
  for (int j = jlo; j < endA; j += 8){
    uint4 w0 = *(const uint4*)&ord_s[j];
    uint4 w1 = *(const uint4*)&ord_s[j + 4];
    c0 += (w0.x>=v0)+(w0.y>=v0)+(w0.z>=v0)+(w0.w>=v0)+(w1.x>=v0)+(w1.y>=v0)+(w1.z>=v0)+(w1.w>=v0);
    c1 += (w0.x>=v1)+(w0.y>=v1)+(w0.z>=v1)+(w0.w>=v1)+(w1.x>=v1)+(w1.y>=v1)+(w1.z>=v1)+(w1.w>=v1);
    c2 += (w0.x>=v2)+(w0.y>=v2)+(w0.z>=v2)+(w0.w>=v2)+(w1.x>=v2)+(w1.y>=v2)+(w1.z>=v2)+(w1.w>=v2);
    c3 += (w0.x>=v3)+(w0.y>=v3)+(w0.z>=v3)+(w0.w>=v3)+(w1.x>=v3)+(w1.y>=v3)+(w1.z>=v3)+(w1.w>=v3);
  }
  int begB = max(jlo, gchunk + 8);
  for (int j = begB; j < jhi; j += 8){
    uint4 w0 = *(const uint4*)&ord_s[j];
    uint4 w1 = *(const uint4*)&ord_s[j + 4];
    c0 += (w0.x>v0)+(w0.y>v0)+(w0.z>v0)+(w0.w>v0)+(w1.x>v0)+(w1.y>v0)+(w1.z>v0)+(w1.w>v0);
    c1 += (w0.x>v1)+(w0.y>v1)+(w0.z>v1)+(w0.w>v1)+(w1.x>v1)+(w1.y>v1)+(w1.z>v1)+(w1.w>v1);
    c2 += (w0.x>v2)+(w0.y>v2)+(w0.z>v2)+(w0.w>v2)+(w1.x>v2)+(w1.y>v2)+(w1.z>v2)+(w1.w>v2);
    c3 += (w0.x>v3)+(w0.y>v3)+(w0.z>v3)+(w0.w>v3)+(w1.x>v3)+(w1.y>v3)+(w1.z>v3)+(w1.w>v3);
  }
  if (gchunk >= jlo && gchunk < jhi){
    int base_off = i0 & 7;       // i0 - gchunk: 0 or 4
    #pragma unroll
    for (int jj = 0; jj < 8; jj++){
      u32 w = ord_s[gchunk + jj];
      c0 += (jj < base_off + 0) ? (w >= v0) : (w > v0);
      c1 += (jj < base_off + 1) ? (w >= v1) : (w > v1);
      c2 += (jj < base_off + 2) ? (w >= v2) : (w > v2);
      c3 += (jj < base_off + 3) ? (w >= v3) : (w > v3);
    }
  }
  int lt = tg << 2;              // local token base
  cnt_s[(js << 7) + lt + 0] = c0;
  cnt_s[(js << 7) + lt + 1] = c1;
  cnt_s[(js << 7) + lt + 2] = c2;
  cnt_s[(js << 7) + lt + 3] = c3;
  __syncthreads();
  if (tid < 128){
    int rank = 0;
    #pragma unroll
    for (int s = 0; s < 8; s++) rank += cnt_s[(s << 7) + tid];
    int i = (slice << 7) + tid;
    if (rank < 512){
      routed[(be << 9) + rank] = i;
      atomicMax(&winner[(b << 12) + i], (rank << 3) | e);   // numpy last-write-wins: max (m,e)
    }
  }
}

// ---------------- fast gathered GEMM: XCD-aware (e = bx&7 -> one expert per XCD) ----------------
__global__ __launch_bounds__(256) void k_gemm_fast(const u16* __restrict__ xb, const u16* __restrict__ WT,
                                                   const float* __restrict__ gates,
                                                   const int* __restrict__ routed,
                                                   const int* __restrict__ winner,
                                                   const int* __restrict__ flag,
                                                   void* __restrict__ outv){
  __shared__ u16 As[128 * 32];
  __shared__ u16 Bs[128 * 32];
  __shared__ int   tok_s[128];
  __shared__ float gate_s[128];
  __shared__ int   flg_s[128];
  int is_f32 = *flag;
  int bx = blockIdx.x;
  // XCD swizzle: consecutive block ids round-robin XCDs; pin e = bx&7 so each XCD
  // works on ONE expert -> its 2 MB WT_e panel stays resident in that XCD's L2.
  int e = bx & 7;
  int rest = bx >> 3;            // 0..127
  int b = rest >> 5;             // 0..3
  int tile = rest & 31;
  int mt = tile & 3, nt = tile >> 2;
  int tid = threadIdx.x;
  int w = tid >> 6, lane = tid & 63;
  int quad = lane >> 4, l16 = lane & 15;

  const int* idx_base = routed + (((b << 3) + e) << 9) + (mt << 7);

  if (tid < 128){
    int tok = idx_base[tid];
    int mg  = (mt << 7) + tid;
    int win = winner[(b << 12) + tok];
    tok_s[tid]  = tok;
    flg_s[tid]  = (win == ((mg << 3) | e)) ? 1 : 0;
    gate_s[tid] = gates[((((size_t)b << 12) + tok) << 3) + e];
  }
  __syncthreads();

  int r0 = tid >> 2;
  int ch = tid & 3;
  int r1 = r0 + 64;
  const u16* gA0 = xb + ((((size_t)b << 12) + tok_s[r0]) << 10) + (ch << 3);
  const u16* gA1 = xb + ((((size_t)b << 12) + tok_s[r1]) << 10) + (ch << 3);
  int f0 = nt << 7;
  const u16* gB0 = WT + ((((size_t)e << 10) + f0 + r0) << 10) + (ch << 3);
  const u16* gB1 = WT + ((((size_t)e << 10) + f0 + r1) << 10) + (ch << 3);

  f32x4 acc[4][4] = {};
  int wm = (w & 1) << 6, wn = (w >> 1) << 6;

  for (int k0 = 0; k0 < 1024; k0 += 32){
    uint4 a0 = *(const uint4*)(gA0 + k0);
    uint4 a1 = *(const uint4*)(gA1 + k0);
    uint4 b0 = *(const uint4*)(gB0 + k0);
    uint4 b1 = *(const uint4*)(gB1 + k0);
    *(uint4*)&As[(r0 << 5) + (ch << 3)] = a0;
    *(uint4*)&As[(r1 << 5) + (ch << 3)] = a1;
    *(uint4*)&Bs[(r0 << 5) + (ch << 3)] = b0;
    *(uint4*)&Bs[(r1 << 5) + (ch << 3)] = b1;
    __syncthreads();
    s16x8 af[4], bv[4];
    #pragma unroll
    for (int im = 0; im < 4; im++)
      af[im] = *(const s16x8*)&As[((wm + (im << 4) + l16) << 5) + (quad << 3)];
    #pragma unroll
    for (int in = 0; in < 4; in++)
      bv[in] = *(const s16x8*)&Bs[((wn + (in << 4) + l16) << 5) + (quad << 3)];
    __syncthreads();
    #pragma unroll
    for (int im = 0; im < 4; im++){
      #pragma unroll
      for (int in = 0; in < 4; in++)
        acc[im][in] = __builtin_amdgcn_mfma_f32_16x16x32_bf16(af[im], bv[in], acc[im][in], 0, 0, 0);
    }
  }

  #pragma unroll
  for (int im = 0; im < 4; im++){
    #pragma unroll
    for (int r = 0; r < 4; r++){
      int mrow = wm + (im << 4) + (quad << 2) + r;
      if (flg_s[mrow]){
        float g  = gate_s[mrow];
        int tok  = tok_s[mrow];
        size_t obase = ((((size_t)b << 12) + tok) << 10) + f0 + wn + l16;
        if (is_f32){
          float* o32 = (float*)outv;
          #pragma unroll
          for (int in = 0; in < 4; in++) o32[obase + (in << 4)] = acc[im][in][r] * g;
        } else {
          u16* o16 = (u16*)outv;
          #pragma unroll
          for (int in = 0; in < 4; in++) o16[obase + (in << 4)] = f2bf(acc[im][in][r] * g);
        }
      }
    }
  }
}

// ---------------- fallback GEMM: on-the-fly convert + LDS transpose (XCD remap too) ----------------
__global__ __launch_bounds__(256) void k_gemm_slow(const void* __restrict__ xv, const void* __restrict__ Wv,
                                                   const float* __restrict__ gates,
                                                   const int* __restrict__ routed,
                                                   const int* __restrict__ winner,
                                                   const int* __restrict__ flag,
                                                   void* __restrict__ outv){
  __shared__ u16 As[128 * 32];
  __shared__ u16 Bw[32 * 132];
  __shared__ u16 Bs[128 * 32];
  __shared__ int   tok_s[128];
  __shared__ float gate_s[128];
  __shared__ int   flg_s[128];
  int is_f32 = *flag;
  int bx = blockIdx.x;
  int e = bx & 7;
  int rest = bx >> 3;
  int b = rest >> 5;
  int tile = rest & 31;
  int mt = tile & 3, nt = tile >> 2;
  int tid = threadIdx.x;
  int w = tid >> 6, lane = tid & 63;
  int quad = lane >> 4, l16 = lane & 15;

  const int* idx_base = routed + (((b << 3) + e) << 9) + (mt << 7);

  if (tid < 128){
    int tok = idx_base[tid];
    int mg  = (mt << 7) + tid;
    int win = winner[(b << 12) + tok];
    tok_s[tid]  = tok;
    flg_s[tid]  = (win == ((mg << 3) | e)) ? 1 : 0;
    gate_s[tid] = gates[((((size_t)b << 12) + tok) << 3) + e];
  }
  __syncthreads();

  int r0 = tid >> 2;
  int ch = tid & 3;
  int r1 = r0 + 64;
  size_t offA0 = ((((size_t)b << 12) + tok_s[r0]) << 10) + (ch << 3);
  size_t offA1 = ((((size_t)b << 12) + tok_s[r1]) << 10) + (ch << 3);
  int f0 = nt << 7;
  int kkB0 = tid >> 4;
  int fcB  = tid & 15;
  size_t offB0 = ((size_t)e << 20) + ((size_t)kkB0 << 10) + f0 + (fcB << 3);
  size_t offB1 = offB0 + ((size_t)16 << 10);
  int f_loc = tid >> 1;
  int half  = tid & 1;

  f32x4 acc[4][4] = {};
  int wm = (w & 1) << 6, wn = (w >> 1) << 6;

  for (int k0 = 0; k0 < 1024; k0 += 32){
    uint4 a0, a1, b0, b1;
    if (is_f32){
      const float* xf = (const float*)xv;
      const float* wf = (const float*)Wv;
      a0 = pack8(*(const float4*)(xf + offA0 + k0), *(const float4*)(xf + offA0 + k0 + 4));
      a1 = pack8(*(const float4*)(xf + offA1 + k0), *(const float4*)(xf + offA1 + k0 + 4));
      b0 = pack8(*(const float4*)(wf + offB0 + ((size_t)k0 << 10)),
                 *(const float4*)(wf + offB0 + ((size_t)k0 << 10) + 4));
      b1 = pack8(*(const float4*)(wf + offB1 + ((size_t)k0 << 10)),
                 *(const float4*)(wf + offB1 + ((size_t)k0 << 10) + 4));
    } else {
      const u16* xh = (const u16*)xv;
      const u16* wh = (const u16*)Wv;
      a0 = *(const uint4*)(xh + offA0 + k0);
      a1 = *(const uint4*)(xh + offA1 + k0);
      b0 = *(const uint4*)(wh + offB0 + ((size_t)k0 << 10));
      b1 = *(const uint4*)(wh + offB1 + ((size_t)k0 << 10));
    }
    *(uint4*)&As[(r0 << 5) + (ch << 3)] = a0;
    *(uint4*)&As[(r1 << 5) + (ch << 3)] = a1;
    *(uint4*)&Bw[kkB0 * 132 + (fcB << 3)] = b0;
    *(uint4*)&Bw[(kkB0 + 16) * 132 + (fcB << 3)] = b1;
    __syncthreads();
    union { uint4 v[2]; u16 s[16]; } tv;
    #pragma unroll
    for (int j = 0; j < 16; j++) tv.s[j] = Bw[((half << 4) + j) * 132 + f_loc];
    *(uint4*)&Bs[(f_loc << 5) + (half << 4)]     = tv.v[0];
    *(uint4*)&Bs[(f_loc << 5) + (half << 4) + 8] = tv.v[1];
    __syncthreads();
    s16x8 af[4], bv[4];
    #pragma unroll
    for (int im = 0; im < 4; im++)
      af[im] = *(const s16x8*)&As[((wm + (im << 4) + l16) << 5) + (quad << 3)];
    #pragma unroll
    for (int in = 0; in < 4; in++)
      bv[in] = *(const s16x8*)&Bs[((wn + (in << 4) + l16) << 5) + (quad << 3)];
    __syncthreads();
    #pragma unroll
    for (int im = 0; im < 4; im++){
      #pragma unroll
      for (int in = 0; in < 4; in++)
        acc[im][in] = __builtin_amdgcn_mfma_f32_16x16x32_bf16(af[im], bv[in], acc[im][in], 0, 0, 0);
    }
  }

  #pragma unroll
  for (int im = 0; im < 4; im++){
    #pragma unroll
    for (int r = 0; r < 4; r++){
      int mrow = wm + (im << 4) + (quad << 2) + r;
      if (flg_s[mrow]){
        float g  = gate_s[mrow];
        int tok  = tok_s[mrow];
        size_t obase = ((((size_t)b << 12) + tok) << 10) + f0 + wn + l16;
        if (is_f32){
          float* o32 = (float*)outv;
          #pragma unroll
          for (int in = 0; in < 4; in++) o32[obase + (in << 4)] = acc[im][in][r] * g;
        } else {
          u16* o16 = (u16*)outv;
          #pragma unroll
          for (int in = 0; in < 4; in++) o16[obase + (in << 4)] = f2bf(acc[im][in][r] * g);
        }
      }
    }
  }
}

extern "C" void kernel_launch(void* const* d_in, const int* in_sizes, int n_in,
                              void* d_out, int out_size, void* d_ws, size_t ws_size,
                              hipStream_t stream){
  const void* x  = d_in[0];   // (4,4096,1024)
  const void* gw = d_in[1];   // (1024,8)
  const void* W  = d_in[2];   // (8,1024,1024)
  char* ws = (char*)d_ws;
  float* gates  = (float*)ws;                               // 524288 B
  int*   winner = (int*)(ws + 524288);                      // 65536 B
  int*   routed = (int*)(ws + 589824);                      // 65536 B
  int*   flag   = (int*)(ws + 655360);                      // 256 B (padded)
  u16*   xb     = (u16*)(ws + 655616);                      // 33554432 B
  u16*   WT     = (u16*)(ws + 655616 + 33554432);           // 16777216 B
  size_t need_fast = 655616ull + 33554432ull + 16777216ull; // ~48.6 MiB
  bool fast = ws_size >= need_fast;

  hipMemsetAsync(winner, 0xFF, 65536, stream);
  hipLaunchKernelGGL(k_detect, dim3(1), dim3(64), 0, stream, (const u32*)x, flag);
  hipLaunchKernelGGL(k_logits_cvt, dim3(2048), dim3(1024), 0, stream,
                     x, gw, flag, xb, gates, fast ? 1 : 0);
  if (fast){
    hipLaunchKernelGGL(k_sink_cover, dim3(1028), dim3(1024), 0, stream,
                       gates, W, flag, WT, (uint4*)d_out, out_size, 1);
    hipLaunchKernelGGL(k_rank, dim3(1024), dim3(256), 0, stream, gates, routed, winner);
    hipLaunchKernelGGL(k_gemm_fast, dim3(1024), dim3(256), 0, stream, xb, WT, gates, routed, winner,
                       flag, d_out);
  } else {
    hipLaunchKernelGGL(k_sink_cover, dim3(516), dim3(1024), 0, stream,
                       gates, W, flag, WT, (uint4*)d_out, out_size, 0);
    hipLaunchKernelGGL(k_rank, dim3(1024), dim3(256), 0, stream, gates, routed, winner);
    hipLaunchKernelGGL(k_gemm_slow, dim3(1024), dim3(256), 0, stream, x, W, gates, routed, winner,
                       flag, d_out);
  }
}

// Round 5
// 276.400 us; speedup vs baseline: 1.8620x; 1.0435x over previous
//
#include <hip/hip_runtime.h>
#include <hip/hip_bf16.h>
#include <stdint.h>

typedef short s16x8 __attribute__((ext_vector_type(8)));
typedef float f32x4 __attribute__((ext_vector_type(4)));
typedef unsigned short u16;
typedef unsigned int u32;
typedef unsigned long long u64;

__device__ __forceinline__ float bf2f(u16 v){
  union { u32 u; float f; } c; c.u = ((u32)v) << 16; return c.f;
}

__device__ __forceinline__ u16 f2bf(float f){
  u32 u = __float_as_uint(f);
  u32 r = (u + 0x7FFFu + ((u >> 16) & 1u)) >> 16;   // round-to-nearest-even
  return (u16)r;
}

__device__ __forceinline__ uint4 pack8(float4 a, float4 b){
  union { uint4 v; u16 s[8]; } o;
  o.s[0]=f2bf(a.x); o.s[1]=f2bf(a.y); o.s[2]=f2bf(a.z); o.s[3]=f2bf(a.w);
  o.s[4]=f2bf(b.x); o.s[5]=f2bf(b.y); o.s[6]=f2bf(b.z); o.s[7]=f2bf(b.w);
  return o.v;
}

// async global->LDS, 16B per lane. LDS dest: wave-uniform base + lane*16.
// Global src is PER-LANE (gather-capable).
__device__ __forceinline__ void gll16(const u16* g, u16* l){
  __builtin_amdgcn_global_load_lds((const __attribute__((address_space(1))) u32*)g,
                                   (__attribute__((address_space(3))) u32*)l, 16, 0, 0);
}

// ---------------- dtype detector: 1 wave, writes flag (1 = fp32 inputs) ----------------
__global__ __launch_bounds__(64) void k_detect(const u32* __restrict__ x, int* __restrict__ flag){
  int lane = threadIdx.x;
  int cnt = 0;
  for (int i = lane; i < 4096; i += 64){
    u32 w = x[i];
    int ex = (w >> 7) & 0xFF;
    cnt += (ex >= 140) ? 1 : 0;
  }
  #pragma unroll
  for (int off = 32; off; off >>= 1) cnt += __shfl_xor(cnt, off, 64);
  if (lane == 0) *flag = (cnt > 256) ? 1 : 0;
}

// ---------------- fused logits + x->bf16 convert ----------------
// 2048 blocks x 1024 threads; block handles 8 tokens. Thread t: token tl=t>>7,
// pos=t&127, loads 8 CONSECUTIVE floats (coalesced), writes xb, partial-dots with
// gw rows pos*8..pos*8+7 from a swizzled LDS copy. Reduction: value-halving
// butterfly (10 shfl) instead of 48-shfl full reduce.
__global__ __launch_bounds__(1024) void k_logits_cvt(const void* __restrict__ xv,
                                                     const void* __restrict__ gwv,
                                                     const int* __restrict__ flag,
                                                     u16* __restrict__ xb,
                                                     float* __restrict__ gates,
                                                     int mode){
  __shared__ float4 gw_swz[2048];   // 32 KB: [p 0..127][c 0..15] swizzled
  __shared__ float  wacc[16][8];
  int is_f32 = *flag;
  int tid = threadIdx.x;

  // ---- stage gw (1024 rows, one per thread), swizzled ----
  {
    int r = tid;
    float g0,g1,g2,g3,g4,g5,g6,g7;
    if (is_f32){
      const float* gw = (const float*)gwv + ((size_t)r << 3);
      float4 u = *(const float4*)gw;
      float4 v = *(const float4*)(gw + 4);
      g0=u.x; g1=u.y; g2=u.z; g3=u.w; g4=v.x; g5=v.y; g6=v.z; g7=v.w;
    } else {
      union { uint4 v; u16 s[8]; } wu;
      wu.v = *(const uint4*)((const u16*)gwv + ((size_t)r << 3));
      g0=bf2f(wu.s[0]); g1=bf2f(wu.s[1]); g2=bf2f(wu.s[2]); g3=bf2f(wu.s[3]);
      g4=bf2f(wu.s[4]); g5=bf2f(wu.s[5]); g6=bf2f(wu.s[6]); g7=bf2f(wu.s[7]);
    }
    int p = r >> 3, j = r & 7;
    gw_swz[(p << 4) + (((j << 1)    ) ^ (p & 15))] = make_float4(g0,g1,g2,g3);
    gw_swz[(p << 4) + (((j << 1) | 1) ^ (p & 15))] = make_float4(g4,g5,g6,g7);
  }

  // ---- load x (8 consecutive floats), write xb ----
  int tl = tid >> 7, pos = tid & 127;
  size_t base = ((((size_t)blockIdx.x << 3) + tl) << 10) + ((size_t)pos << 3);
  float xf[8];
  if (is_f32){
    const float* xr = (const float*)xv + base;
    float4 u = *(const float4*)xr;
    float4 v = *(const float4*)(xr + 4);
    xf[0]=u.x; xf[1]=u.y; xf[2]=u.z; xf[3]=u.w;
    xf[4]=v.x; xf[5]=v.y; xf[6]=v.z; xf[7]=v.w;
    if (mode) *(uint4*)(xb + base) = pack8(u, v);
  } else {
    uint4 raw = *(const uint4*)((const u16*)xv + base);
    union { uint4 v; u16 s[8]; } xu; xu.v = raw;
    #pragma unroll
    for (int k = 0; k < 8; k++) xf[k] = bf2f(xu.s[k]);
    if (mode) *(uint4*)(xb + base) = raw;
  }
  __syncthreads();

  // ---- dot: acc[e] = sum_j xf[j] * gw[pos*8+j][e] ----
  float a0=0,a1=0,a2=0,a3=0,a4=0,a5=0,a6=0,a7=0;
  #pragma unroll
  for (int j = 0; j < 8; j++){
    float4 wA = gw_swz[(pos << 4) + (((j << 1)    ) ^ (pos & 15))];
    float4 wB = gw_swz[(pos << 4) + (((j << 1) | 1) ^ (pos & 15))];
    float xv8 = xf[j];
    a0 += xv8*wA.x; a1 += xv8*wA.y; a2 += xv8*wA.z; a3 += xv8*wA.w;
    a4 += xv8*wB.x; a5 += xv8*wB.y; a6 += xv8*wB.z; a7 += xv8*wB.w;
  }
  int wave = tid >> 6, lane = tid & 63;
  // ---- value-halving butterfly: after 3 levels lane holds one e; 3 more combine groups ----
  int s1 = lane & 1;
  float k0 = s1 ? a4 : a0, g0 = s1 ? a0 : a4;
  float k1 = s1 ? a5 : a1, g1 = s1 ? a1 : a5;
  float k2 = s1 ? a6 : a2, g2 = s1 ? a2 : a6;
  float k3 = s1 ? a7 : a3, g3 = s1 ? a3 : a7;
  k0 += __shfl_xor(g0, 1, 64); k1 += __shfl_xor(g1, 1, 64);
  k2 += __shfl_xor(g2, 1, 64); k3 += __shfl_xor(g3, 1, 64);
  int s2 = (lane >> 1) & 1;
  float m0 = s2 ? k2 : k0, h0 = s2 ? k0 : k2;
  float m1 = s2 ? k3 : k1, h1 = s2 ? k1 : k3;
  m0 += __shfl_xor(h0, 2, 64); m1 += __shfl_xor(h1, 2, 64);
  int s3 = (lane >> 2) & 1;
  float r = s3 ? m1 : m0, h = s3 ? m0 : m1;
  r += __shfl_xor(h, 4, 64);
  r += __shfl_xor(r, 8, 64);
  r += __shfl_xor(r, 16, 64);
  r += __shfl_xor(r, 32, 64);
  if (lane < 8){
    int e = ((lane & 1) << 2) | (lane & 2) | ((lane >> 2) & 1);
    wacc[wave][e] = r;
  }
  __syncthreads();
  if (tid < 64){
    int tt = tid >> 3, e = tid & 7;
    float v = wacc[(tt << 1)][e] + wacc[(tt << 1) | 1][e];
    gates[((((size_t)blockIdx.x << 3) + tt) << 3) + e] = v;
  }
}

// ---------------- fused: sinkhorn (blocks 0-3) + cvt_wt + zero cover ----------------
__global__ __launch_bounds__(1024) void k_sink_cover(float* __restrict__ gates,
                                                     const void* __restrict__ Wv,
                                                     const int* __restrict__ flag,
                                                     u16* __restrict__ WT,
                                                     uint4* __restrict__ out,
                                                     int out_size, int mode){
  __shared__ __align__(16) char smem[36864];
  int bx = blockIdx.x;
  int tid = threadIdx.x;

  if (bx < 4){
    float* wred = (float*)smem;      // [16][8]
    float* lbc  = wred + 128;        // [8]
    int wave = tid >> 6, lane = tid & 63;
    float* gb = gates + ((size_t)bx << 15);
    float4 va[4], vb[4];
    #pragma unroll
    for (int q = 0; q < 4; q++){
      float* gp = gb + (((q << 10) + tid) << 3);
      float4 a = *(const float4*)gp;
      float4 b = *(const float4*)(gp + 4);
      a.x=fmaxf(a.x,1e-6f); a.y=fmaxf(a.y,1e-6f); a.z=fmaxf(a.z,1e-6f); a.w=fmaxf(a.w,1e-6f);
      b.x=fmaxf(b.x,1e-6f); b.y=fmaxf(b.y,1e-6f); b.z=fmaxf(b.z,1e-6f); b.w=fmaxf(b.w,1e-6f);
      va[q]=a; vb[q]=b;
    }
    for (int it = 0; it < 8; it++){
      float s0 = ((va[0].x+va[1].x)+(va[2].x+va[3].x));
      float s1 = ((va[0].y+va[1].y)+(va[2].y+va[3].y));
      float s2 = ((va[0].z+va[1].z)+(va[2].z+va[3].z));
      float s3 = ((va[0].w+va[1].w)+(va[2].w+va[3].w));
      float s4 = ((vb[0].x+vb[1].x)+(vb[2].x+vb[3].x));
      float s5 = ((vb[0].y+vb[1].y)+(vb[2].y+vb[3].y));
      float s6 = ((vb[0].z+vb[1].z)+(vb[2].z+vb[3].z));
      float s7 = ((vb[0].w+vb[1].w)+(vb[2].w+vb[3].w));
      #pragma unroll
      for (int off = 32; off; off >>= 1){
        s0 += __shfl_xor(s0, off, 64); s1 += __shfl_xor(s1, off, 64);
        s2 += __shfl_xor(s2, off, 64); s3 += __shfl_xor(s3, off, 64);
        s4 += __shfl_xor(s4, off, 64); s5 += __shfl_xor(s5, off, 64);
        s6 += __shfl_xor(s6, off, 64); s7 += __shfl_xor(s7, off, 64);
      }
      if (lane == 0){
        wred[(wave<<3)+0]=s0; wred[(wave<<3)+1]=s1; wred[(wave<<3)+2]=s2; wred[(wave<<3)+3]=s3;
        wred[(wave<<3)+4]=s4; wred[(wave<<3)+5]=s5; wred[(wave<<3)+6]=s6; wred[(wave<<3)+7]=s7;
      }
      __syncthreads();
      if (tid < 8){
        float S = 0.f;
        #pragma unroll
        for (int w2 = 0; w2 < 16; w2++) S += wred[(w2 << 3) + tid];
        lbc[tid] = 1.0f / S;
      }
      __syncthreads();
      float i0=lbc[0], i1=lbc[1], i2=lbc[2], i3=lbc[3];
      float i4=lbc[4], i5=lbc[5], i6=lbc[6], i7=lbc[7];
      #pragma unroll
      for (int q = 0; q < 4; q++){
        float4 a = va[q], b = vb[q];
        a.x*=i0; a.y*=i1; a.z*=i2; a.w*=i3;
        b.x*=i4; b.y*=i5; b.z*=i6; b.w*=i7;
        float rs = ((a.x+a.y)+(a.z+a.w)) + ((b.x+b.y)+(b.z+b.w));
        float ir = 1.0f / rs;
        a.x*=ir; a.y*=ir; a.z*=ir; a.w*=ir;
        b.x*=ir; b.y*=ir; b.z*=ir; b.w*=ir;
        va[q]=a; vb[q]=b;
      }
    }
    #pragma unroll
    for (int q = 0; q < 4; q++){
      float* gp = gb + (((q << 10) + tid) << 3);
      *(float4*)gp = va[q];
      *(float4*)(gp + 4) = vb[q];
    }
    return;
  }

  if (mode == 0){
    int is_f32 = *flag;
    int rb = bx - 4;
    size_t words = (size_t)out_size >> (is_f32 ? 0 : 1);
    size_t n4 = words >> 2;
    size_t i = (size_t)rb * 1024 + tid;
    uint4 z = make_uint4(0, 0, 0, 0);
    for (; i < n4; i += (size_t)512 * 1024) out[i] = z;
    return;
  }

  if (bx < 516){
    // ---- W (e,d,f) -> WT (e,f,d) bf16: 4 64x64 tiles per block ----
    int is_f32 = *flag;
    int rb = bx - 4;
    int sub = tid >> 8;
    int t = tid & 255;
    int g = (rb << 2) + sub;          // global tile id 0..2047
    int e = g >> 8, t2 = g & 255;
    int td = (t2 >> 4) << 6, tf = (t2 & 15) << 6;
    u16 (*tile)[72] = (u16(*)[72])(smem + (size_t)sub * (64 * 72 * 2));
    #pragma unroll
    for (int i = 0; i < 2; i++){
      int id = t + (i << 8);
      int row = id >> 3, c8 = id & 7;
      size_t src = ((size_t)(e*1024 + td + row))*1024 + tf + (c8 << 3);
      uint4 v;
      if (is_f32){
        const float* wf = (const float*)Wv;
        v = pack8(*(const float4*)(wf + src), *(const float4*)(wf + src + 4));
      } else {
        v = *(const uint4*)((const u16*)Wv + src);
      }
      *(uint4*)&tile[row][c8 << 3] = v;
    }
    __syncthreads();
    #pragma unroll
    for (int i = 0; i < 2; i++){
      int id = t + (i << 8);
      int frow = id >> 3, c8 = id & 7;
      union { uint4 v; u16 s[8]; } o;
      #pragma unroll
      for (int j = 0; j < 8; j++) o.s[j] = tile[(c8 << 3) + j][frow];
      *(uint4*)(WT + ((size_t)(e*1024 + tf + frow))*1024 + td + (c8 << 3)) = o.v;
    }
    return;
  }

  {
    // ---- zero-fill d_out ----
    int is_f32 = *flag;
    int rb = bx - 516;
    size_t words = (size_t)out_size >> (is_f32 ? 0 : 1);
    size_t n4 = words >> 2;
    size_t i = (size_t)rb * 1024 + tid;
    uint4 z = make_uint4(0, 0, 0, 0);
    for (; i < n4; i += (size_t)512 * 1024) out[i] = z;
  }
}

// ---------------- top-512 via exact rank-by-counting, v2 ----------------
__global__ __launch_bounds__(256) void k_rank(const float* __restrict__ gates,
                                              int* __restrict__ routed, int* __restrict__ winner){
  __shared__ u32 ord_s[4096];
  __shared__ u32 cnt_s[1024];    // [js][local_token]
  int bx = blockIdx.x;
  int be = bx >> 5;              // 0..31
  int b = be >> 3, e = be & 7;
  int slice = bx & 31;           // 0..31
  int tid = threadIdx.x;
  const float* gb = gates + (size_t)b * (4096 * 8);
  for (int i = tid; i < 4096; i += 256){
    float v = gb[(i << 3) + e];
    u32 fb = __float_as_uint(v);
    ord_s[i] = fb ^ ((fb >> 31) ? 0xFFFFFFFFu : 0x80000000u);   // monotone total order
  }
  __syncthreads();

  int tg = tid & 31;             // token group: 4 tokens
  int js = tid >> 5;             // j-slice: 0..7, 512 j's each
  int i0 = (slice << 7) + (tg << 2);          // first of my 4 tokens (4-aligned)
  int gchunk = i0 & ~7;                       // the 8-chunk containing all 4 tokens
  u32 v0 = ord_s[i0], v1 = ord_s[i0+1], v2 = ord_s[i0+2], v3 = ord_s[i0+3];
  int jlo = js << 9, jhi = jlo + 512;
  int c0 = 0, c1 = 0, c2 = 0, c3 = 0;

  int endA = min(jhi, gchunk);
  for (int j = jlo; j < endA; j += 8){
    uint4 w0 = *(const uint4*)&ord_s[j];
    uint4 w1 = *(const uint4*)&ord_s[j + 4];
    c0 += (w0.x>=v0)+(w0.y>=v0)+(w0.z>=v0)+(w0.w>=v0)+(w1.x>=v0)+(w1.y>=v0)+(w1.z>=v0)+(w1.w>=v0);
    c1 += (w0.x>=v1)+(w0.y>=v1)+(w0.z>=v1)+(w0.w>=v1)+(w1.x>=v1)+(w1.y>=v1)+(w1.z>=v1)+(w1.w>=v1);
    c2 += (w0.x>=v2)+(w0.y>=v2)+(w0.z>=v2)+(w0.w>=v2)+(w1.x>=v2)+(w1.y>=v2)+(w1.z>=v2)+(w1.w>=v2);
    c3 += (w0.x>=v3)+(w0.y>=v3)+(w0.z>=v3)+(w0.w>=v3)+(w1.x>=v3)+(w1.y>=v3)+(w1.z>=v3)+(w1.w>=v3);
  }
  int begB = max(jlo, gchunk + 8);
  for (int j = begB; j < jhi; j += 8){
    uint4 w0 = *(const uint4*)&ord_s[j];
    uint4 w1 = *(const uint4*)&ord_s[j + 4];
    c0 += (w0.x>v0)+(w0.y>v0)+(w0.z>v0)+(w0.w>v0)+(w1.x>v0)+(w1.y>v0)+(w1.z>v0)+(w1.w>v0);
    c1 += (w0.x>v1)+(w0.y>v1)+(w0.z>v1)+(w0.w>v1)+(w1.x>v1)+(w1.y>v1)+(w1.z>v1)+(w1.w>v1);
    c2 += (w0.x>v2)+(w0.y>v2)+(w0.z>v2)+(w0.w>v2)+(w1.x>v2)+(w1.y>v2)+(w1.z>v2)+(w1.w>v2);
    c3 += (w0.x>v3)+(w0.y>v3)+(w0.z>v3)+(w0.w>v3)+(w1.x>v3)+(w1.y>v3)+(w1.z>v3)+(w1.w>v3);
  }
  if (gchunk >= jlo && gchunk < jhi){
    int base_off = i0 & 7;       // i0 - gchunk: 0 or 4
    #pragma unroll
    for (int jj = 0; jj < 8; jj++){
      u32 w = ord_s[gchunk + jj];
      c0 += (jj < base_off + 0) ? (w >= v0) : (w > v0);
      c1 += (jj < base_off + 1) ? (w >= v1) : (w > v1);
      c2 += (jj < base_off + 2) ? (w >= v2) : (w > v2);
      c3 += (jj < base_off + 3) ? (w >= v3) : (w > v3);
    }
  }
  int lt = tg << 2;              // local token base
  cnt_s[(js << 7) + lt + 0] = c0;
  cnt_s[(js << 7) + lt + 1] = c1;
  cnt_s[(js << 7) + lt + 2] = c2;
  cnt_s[(js << 7) + lt + 3] = c3;
  __syncthreads();
  if (tid < 128){
    int rank = 0;
    #pragma unroll
    for (int s = 0; s < 8; s++) rank += cnt_s[(s << 7) + tid];
    int i = (slice << 7) + tid;
    if (rank < 512){
      routed[(be << 9) + rank] = i;
      atomicMax(&winner[(b << 12) + i], (rank << 3) | e);   // numpy last-write-wins: max (m,e)
    }
  }
}

// ---------------- fast gathered GEMM v2: global_load_lds + XOR-swizzled fragments ----------------
// XCD-pinned (e = bx&7). Staging via global_load_lds width=16 (no VGPR roundtrip).
// Swizzle is BOTH-sides (rule #21): source chunk ch^((row>>1)&3) pre-applied to the
// per-lane GLOBAL address (LDS dest stays linear); ds_read applies the same involution.
// Removes the 8-way row-stride bank aliasing on fragment reads.
__global__ __launch_bounds__(256) void k_gemm_fast(const u16* __restrict__ xb, const u16* __restrict__ WT,
                                                   const float* __restrict__ gates,
                                                   const int* __restrict__ routed,
                                                   const int* __restrict__ winner,
                                                   const int* __restrict__ flag,
                                                   void* __restrict__ outv){
  __shared__ u16 As[128 * 32];
  __shared__ u16 Bs[128 * 32];
  __shared__ int   tok_s[128];
  __shared__ float gate_s[128];
  __shared__ int   flg_s[128];
  int is_f32 = *flag;
  int bx = blockIdx.x;
  int e = bx & 7;
  int rest = bx >> 3;            // 0..127
  int b = rest >> 5;             // 0..3
  int tile = rest & 31;
  int mt = tile & 3, nt = tile >> 2;
  int tid = threadIdx.x;
  int w = tid >> 6, lane = tid & 63;
  int quad = lane >> 4, l16 = lane & 15;

  const int* idx_base = routed + (((b << 3) + e) << 9) + (mt << 7);

  if (tid < 128){
    int tok = idx_base[tid];
    int mg  = (mt << 7) + tid;
    int win = winner[(b << 12) + tok];
    tok_s[tid]  = tok;
    flg_s[tid]  = (win == ((mg << 3) | e)) ? 1 : 0;
    gate_s[tid] = gates[((((size_t)b << 12) + tok) << 3) + e];
  }
  __syncthreads();

  int r0 = tid >> 2;             // staged row (0..63); row r0+64 staged to second half
  int ch = tid & 3;              // 16B chunk within the 32-elem K-step
  int r1 = r0 + 64;
  int swz = ch ^ ((r0 >> 1) & 3);           // source pre-swizzle ((r1>>1)&3 == (r0>>1)&3)
  const u16* gA0 = xb + ((((size_t)b << 12) + tok_s[r0]) << 10) + (swz << 3);
  const u16* gA1 = xb + ((((size_t)b << 12) + tok_s[r1]) << 10) + (swz << 3);
  int f0 = nt << 7;
  const u16* gB0 = WT + ((((size_t)e << 10) + f0 + r0) << 10) + (swz << 3);
  const u16* gB1 = WT + ((((size_t)e << 10) + f0 + r1) << 10) + (swz << 3);
  // wave-uniform LDS bases: lane l lands at base + l*16B
  u16* lA0 = As + (w << 9);
  u16* lA1 = As + 2048 + (w << 9);
  u16* lB0 = Bs + (w << 9);
  u16* lB1 = Bs + 2048 + (w << 9);
  int swzr = quad ^ ((l16 >> 1) & 3);       // read-side involution (row-dependent part = (l16>>1)&3)

  f32x4 acc[4][4] = {};
  int wm = (w & 1) << 6, wn = (w >> 1) << 6;

  for (int k0 = 0; k0 < 1024; k0 += 32){
    gll16(gA0 + k0, lA0);
    gll16(gA1 + k0, lA1);
    gll16(gB0 + k0, lB0);
    gll16(gB1 + k0, lB1);
    __syncthreads();
    s16x8 af[4], bv[4];
    #pragma unroll
    for (int im = 0; im < 4; im++)
      af[im] = *(const s16x8*)&As[((wm + (im << 4) + l16) << 5) + (swzr << 3)];
    #pragma unroll
    for (int in = 0; in < 4; in++)
      bv[in] = *(const s16x8*)&Bs[((wn + (in << 4) + l16) << 5) + (swzr << 3)];
    __syncthreads();
    #pragma unroll
    for (int im = 0; im < 4; im++){
      #pragma unroll
      for (int in = 0; in < 4; in++)
        acc[im][in] = __builtin_amdgcn_mfma_f32_16x16x32_bf16(af[im], bv[in], acc[im][in], 0, 0, 0);
    }
  }

  #pragma unroll
  for (int im = 0; im < 4; im++){
    #pragma unroll
    for (int r = 0; r < 4; r++){
      int mrow = wm + (im << 4) + (quad << 2) + r;
      if (flg_s[mrow]){
        float g  = gate_s[mrow];
        int tok  = tok_s[mrow];
        size_t obase = ((((size_t)b << 12) + tok) << 10) + f0 + wn + l16;
        if (is_f32){
          float* o32 = (float*)outv;
          #pragma unroll
          for (int in = 0; in < 4; in++) o32[obase + (in << 4)] = acc[im][in][r] * g;
        } else {
          u16* o16 = (u16*)outv;
          #pragma unroll
          for (int in = 0; in < 4; in++) o16[obase + (in << 4)] = f2bf(acc[im][in][r] * g);
        }
      }
    }
  }
}

// ---------------- fallback GEMM: on-the-fly convert + LDS transpose (XCD remap) ----------------
__global__ __launch_bounds__(256) void k_gemm_slow(const void* __restrict__ xv, const void* __restrict__ Wv,
                                                   const float* __restrict__ gates,
                                                   const int* __restrict__ routed,
                                                   const int* __restrict__ winner,
                                                   const int* __restrict__ flag,
                                                   void* __restrict__ outv){
  __shared__ u16 As[128 * 32];
  __shared__ u16 Bw[32 * 132];
  __shared__ u16 Bs[128 * 32];
  __shared__ int   tok_s[128];
  __shared__ float gate_s[128];
  __shared__ int   flg_s[128];
  int is_f32 = *flag;
  int bx = blockIdx.x;
  int e = bx & 7;
  int rest = bx >> 3;
  int b = rest >> 5;
  int tile = rest & 31;
  int mt = tile & 3, nt = tile >> 2;
  int tid = threadIdx.x;
  int w = tid >> 6, lane = tid & 63;
  int quad = lane >> 4, l16 = lane & 15;

  const int* idx_base = routed + (((b << 3) + e) << 9) + (mt << 7);

  if (tid < 128){
    int tok = idx_base[tid];
    int mg  = (mt << 7) + tid;
    int win = winner[(b << 12) + tok];
    tok_s[tid]  = tok;
    flg_s[tid]  = (win == ((mg << 3) | e)) ? 1 : 0;
    gate_s[tid] = gates[((((size_t)b << 12) + tok) << 3) + e];
  }
  __syncthreads();

  int r0 = tid >> 2;
  int ch = tid & 3;
  int r1 = r0 + 64;
  size_t offA0 = ((((size_t)b << 12) + tok_s[r0]) << 10) + (ch << 3);
  size_t offA1 = ((((size_t)b << 12) + tok_s[r1]) << 10) + (ch << 3);
  int f0 = nt << 7;
  int kkB0 = tid >> 4;
  int fcB  = tid & 15;
  size_t offB0 = ((size_t)e << 20) + ((size_t)kkB0 << 10) + f0 + (fcB << 3);
  size_t offB1 = offB0 + ((size_t)16 << 10);
  int f_loc = tid >> 1;
  int half  = tid & 1;

  f32x4 acc[4][4] = {};
  int wm = (w & 1) << 6, wn = (w >> 1) << 6;

  for (int k0 = 0; k0 < 1024; k0 += 32){
    uint4 a0, a1, b0, b1;
    if (is_f32){
      const float* xf = (const float*)xv;
      const float* wf = (const float*)Wv;
      a0 = pack8(*(const float4*)(xf + offA0 + k0), *(const float4*)(xf + offA0 + k0 + 4));
      a1 = pack8(*(const float4*)(xf + offA1 + k0), *(const float4*)(xf + offA1 + k0 + 4));
      b0 = pack8(*(const float4*)(wf + offB0 + ((size_t)k0 << 10)),
                 *(const float4*)(wf + offB0 + ((size_t)k0 << 10) + 4));
      b1 = pack8(*(const float4*)(wf + offB1 + ((size_t)k0 << 10)),
                 *(const float4*)(wf + offB1 + ((size_t)k0 << 10) + 4));
    } else {
      const u16* xh = (const u16*)xv;
      const u16* wh = (const u16*)Wv;
      a0 = *(const uint4*)(xh + offA0 + k0);
      a1 = *(const uint4*)(xh + offA1 + k0);
      b0 = *(const uint4*)(wh + offB0 + ((size_t)k0 << 10));
      b1 = *(const uint4*)(wh + offB1 + ((size_t)k0 << 10));
    }
    *(uint4*)&As[(r0 << 5) + (ch << 3)] = a0;
    *(uint4*)&As[(r1 << 5) + (ch << 3)] = a1;
    *(uint4*)&Bw[kkB0 * 132 + (fcB << 3)] = b0;
    *(uint4*)&Bw[(kkB0 + 16) * 132 + (fcB << 3)] = b1;
    __syncthreads();
    union { uint4 v[2]; u16 s[16]; } tv;
    #pragma unroll
    for (int j = 0; j < 16; j++) tv.s[j] = Bw[((half << 4) + j) * 132 + f_loc];
    *(uint4*)&Bs[(f_loc << 5) + (half << 4)]     = tv.v[0];
    *(uint4*)&Bs[(f_loc << 5) + (half << 4) + 8] = tv.v[1];
    __syncthreads();
    s16x8 af[4], bv[4];
    #pragma unroll
    for (int im = 0; im < 4; im++)
      af[im] = *(const s16x8*)&As[((wm + (im << 4) + l16) << 5) + (quad << 3)];
    #pragma unroll
    for (int in = 0; in < 4; in++)
      bv[in] = *(const s16x8*)&Bs[((wn + (in << 4) + l16) << 5) + (quad << 3)];
    __syncthreads();
    #pragma unroll
    for (int im = 0; im < 4; im++){
      #pragma unroll
      for (int in = 0; in < 4; in++)
        acc[im][in] = __builtin_amdgcn_mfma_f32_16x16x32_bf16(af[im], bv[in], acc[im][in], 0, 0, 0);
    }
  }

  #pragma unroll
  for (int im = 0; im < 4; im++){
    #pragma unroll
    for (int r = 0; r < 4; r++){
      int mrow = wm + (im << 4) + (quad << 2) + r;
      if (flg_s[mrow]){
        float g  = gate_s[mrow];
        int tok  = tok_s[mrow];
        size_t obase = ((((size_t)b << 12) + tok) << 10) + f0 + wn + l16;
        if (is_f32){
          float* o32 = (float*)outv;
          #pragma unroll
          for (int in = 0; in < 4; in++) o32[obase + (in << 4)] = acc[im][in][r] * g;
        } else {
          u16* o16 = (u16*)outv;
          #pragma unroll
          for (int in = 0; in < 4; in++) o16[obase + (in << 4)] = f2bf(acc[im][in][r] * g);
        }
      }
    }
  }
}

extern "C" void kernel_launch(void* const* d_in, const int* in_sizes, int n_in,
                              void* d_out, int out_size, void* d_ws, size_t ws_size,
                              hipStream_t stream){
  const void* x  = d_in[0];   // (4,4096,1024)
  const void* gw = d_in[1];   // (1024,8)
  const void* W  = d_in[2];   // (8,1024,1024)
  char* ws = (char*)d_ws;
  float* gates  = (float*)ws;                               // 524288 B
  int*   winner = (int*)(ws + 524288);                      // 65536 B
  int*   routed = (int*)(ws + 589824);                      // 65536 B
  int*   flag   = (int*)(ws + 655360);                      // 256 B (padded)
  u16*   xb     = (u16*)(ws + 655616);                      // 33554432 B
  u16*   WT     = (u16*)(ws + 655616 + 33554432);           // 16777216 B
  size_t need_fast = 655616ull + 33554432ull + 16777216ull; // ~48.6 MiB
  bool fast = ws_size >= need_fast;

  hipMemsetAsync(winner, 0xFF, 65536, stream);
  hipLaunchKernelGGL(k_detect, dim3(1), dim3(64), 0, stream, (const u32*)x, flag);
  hipLaunchKernelGGL(k_logits_cvt, dim3(2048), dim3(1024), 0, stream,
                     x, gw, flag, xb, gates, fast ? 1 : 0);
  if (fast){
    hipLaunchKernelGGL(k_sink_cover, dim3(1028), dim3(1024), 0, stream,
                       gates, W, flag, WT, (uint4*)d_out, out_size, 1);
    hipLaunchKernelGGL(k_rank, dim3(1024), dim3(256), 0, stream, gates, routed, winner);
    hipLaunchKernelGGL(k_gemm_fast, dim3(1024), dim3(256), 0, stream, xb, WT, gates, routed, winner,
                       flag, d_out);
  } else {
    hipLaunchKernelGGL(k_sink_cover, dim3(516), dim3(1024), 0, stream,
                       gates, W, flag, WT, (uint4*)d_out, out_size, 0);
    hipLaunchKernelGGL(k_rank, dim3(1024), dim3(256), 0, stream, gates, routed, winner);
    hipLaunchKernelGGL(k_gemm_slow, dim3(1024), dim3(256), 0, stream, x, W, gates, routed, winner,
                       flag, d_out);
  }
}